// Round 2
// baseline (1949.442 us; speedup 1.0000x reference)
//
#include <hip/hip_runtime.h>
#include <hip/hip_bf16.h>

#define NN 50000
#define NE 400000

// ---------- CSR build ----------
__global__ void hist_kernel(const int* __restrict__ dst, int* __restrict__ deg) {
    int e = blockIdx.x * blockDim.x + threadIdx.x;
    if (e < NE) atomicAdd(&deg[dst[e]], 1);
}

__global__ void scan_kernel(const int* __restrict__ deg, int* __restrict__ off,
                            int* __restrict__ cur, int n) {
    __shared__ int sm[1024];
    __shared__ int carry_s;
    if (threadIdx.x == 0) carry_s = 0;
    __syncthreads();
    for (int base = 0; base < n; base += 1024) {
        int i = base + (int)threadIdx.x;
        int v = (i < n) ? deg[i] : 0;
        sm[threadIdx.x] = v;
        __syncthreads();
        for (int o = 1; o < 1024; o <<= 1) {
            int t = (threadIdx.x >= (unsigned)o) ? sm[threadIdx.x - o] : 0;
            __syncthreads();
            sm[threadIdx.x] += t;
            __syncthreads();
        }
        int carry = carry_s;
        int excl = carry + sm[threadIdx.x] - v;
        if (i < n) { off[i] = excl; cur[i] = excl; }
        __syncthreads();
        if (threadIdx.x == 1023) carry_s = carry + sm[1023];
        __syncthreads();
    }
    if (threadIdx.x == 0) off[n] = carry_s;
}

__global__ void scatter_kernel(const int* __restrict__ src, const int* __restrict__ dst,
                               int* __restrict__ cur, int* __restrict__ csr_src) {
    int e = blockIdx.x * blockDim.x + threadIdx.x;
    if (e < NE) {
        int p = atomicAdd(&cur[dst[e]], 1);
        csr_src[p] = src[e];
    }
}

// ---------- fp32 tiled GEMM: C[M,Nc] = A[M,K] @ B[K,Nc] ----------
__global__ __launch_bounds__(256) void gemm_f32(const float* __restrict__ A,
                                                const float* __restrict__ B,
                                                float* __restrict__ C,
                                                int M, int Nc, int K) {
    const int BM = 64, BN = 64, BK = 16, TM = 4, TN = 4;
    __shared__ float As[BK][BM + 1];
    __shared__ float Bs[BK][BN + 1];
    int tx = threadIdx.x % 16, ty = threadIdx.x / 16;
    int row0 = blockIdx.x * BM;
    int col0 = blockIdx.y * BN;
    float acc[TM][TN] = {};
    for (int k0 = 0; k0 < K; k0 += BK) {
        for (int i = threadIdx.x; i < BM * BK; i += 256) {
            int r2 = i / BK, k2 = i % BK;
            float v = (row0 + r2 < M) ? A[(size_t)(row0 + r2) * K + k0 + k2] : 0.f;
            As[k2][r2] = v;
        }
        for (int i = threadIdx.x; i < BK * BN; i += 256) {
            int k2 = i / BN, c2 = i % BN;
            float v = (col0 + c2 < Nc) ? B[(size_t)(k0 + k2) * Nc + col0 + c2] : 0.f;
            Bs[k2][c2] = v;
        }
        __syncthreads();
#pragma unroll
        for (int kk = 0; kk < BK; ++kk) {
            float a[TM], b[TN];
#pragma unroll
            for (int i = 0; i < TM; i++) a[i] = As[kk][ty * TM + i];
#pragma unroll
            for (int j = 0; j < TN; j++) b[j] = Bs[kk][tx * TN + j];
#pragma unroll
            for (int i = 0; i < TM; i++)
#pragma unroll
                for (int j = 0; j < TN; j++) acc[i][j] += a[i] * b[j];
        }
        __syncthreads();
    }
    for (int i = 0; i < TM; i++) {
        int r = row0 + ty * TM + i;
        if (r >= M) continue;
        for (int j = 0; j < TN; j++) {
            int c = col0 + tx * TN + j;
            if (c < Nc) C[(size_t)r * Nc + c] = acc[i][j];
        }
    }
}

// ---------- attention coefficients: el[n,h] = sum_d feat[n,h,d]*al[h,d] ----------
__global__ __launch_bounds__(256) void attn_kernel(const float* __restrict__ feat,
                                                   const float* __restrict__ al,
                                                   const float* __restrict__ ar,
                                                   float* __restrict__ el, float* __restrict__ er,
                                                   int H, int D) {
    int wid = (blockIdx.x * blockDim.x + threadIdx.x) >> 6;
    int lane = threadIdx.x & 63;
    if (wid >= NN * H) return;
    int n = wid / H, h = wid - n * H;
    float pl = 0.f, pr = 0.f;
    if (lane < D) {
        float v = feat[(size_t)n * H * D + h * D + lane];
        pl = v * al[h * D + lane];
        pr = v * ar[h * D + lane];
    }
    for (int o = 32; o; o >>= 1) {
        pl += __shfl_down(pl, o, 64);
        pr += __shfl_down(pr, o, 64);
    }
    if (lane == 0) { el[wid] = pl; er[wid] = pr; }
}

// ---------- per-(node,head) online-softmax aggregation over dst-CSR ----------
__global__ __launch_bounds__(256) void agg_kernel(const float* __restrict__ feat,
                                                  const float* __restrict__ el,
                                                  const float* __restrict__ er,
                                                  const int* __restrict__ off,
                                                  const int* __restrict__ csr_src,
                                                  float* __restrict__ out,
                                                  int H, int D) {
    int wid = (blockIdx.x * blockDim.x + threadIdx.x) >> 6;
    int lane = threadIdx.x & 63;
    if (wid >= NN * H) return;
    int n = wid / H, h = wid - n * H;
    int rs = off[n], re = off[n + 1];
    float er_n = er[wid];
    float m = -INFINITY, l = 0.f, acc = 0.f;
    for (int base = rs; base < re; base += 64) {
        int cnt = min(64, re - base);
        int s = 0;
        float x = -INFINITY;
        if (lane < cnt) {
            s = csr_src[base + lane];
            float t = el[s * H + h] + er_n;
            x = (t >= 0.f) ? t : 0.2f * t;
        }
        float cm = x;
        for (int o = 32; o; o >>= 1) cm = fmaxf(cm, __shfl_xor(cm, o, 64));
        float nm = fmaxf(m, cm);
        float scale = __expf(m - nm);  // m=-inf -> 0
        float p = (lane < cnt) ? __expf(x - nm) : 0.f;
        float cl = p;
        for (int o = 32; o; o >>= 1) cl += __shfl_xor(cl, o, 64);
        l = l * scale + cl;
        acc *= scale;
        for (int i = 0; i < cnt; ++i) {
            float pi = __shfl(p, i, 64);
            int si = __shfl(s, i, 64);
            if (lane < D) acc += pi * feat[(size_t)si * H * D + h * D + lane];
        }
        m = nm;
    }
    float res = (l > 0.f) ? acc / l : 0.f;
    if (lane < D) out[(size_t)n * H * D + h * D + lane] = res;
}

extern "C" void kernel_launch(void* const* d_in, const int* in_sizes, int n_in,
                              void* d_out, int out_size, void* d_ws, size_t ws_size,
                              hipStream_t stream) {
    const float* features = (const float*)d_in[0];
    const int* src = (const int*)d_in[1];
    const int* dst = (const int*)d_in[2];
    const float* W1 = (const float*)d_in[3];
    const float* al1 = (const float*)d_in[4];
    const float* ar1 = (const float*)d_in[5];
    const float* W2 = (const float*)d_in[6];
    const float* al2 = (const float*)d_in[7];
    const float* ar2 = (const float*)d_in[8];
    const float* W3 = (const float*)d_in[9];
    const float* al3 = (const float*)d_in[10];
    const float* ar3 = (const float*)d_in[11];

    char* ws = (char*)d_ws;
    size_t o = 0;
    auto carve = [&](size_t bytes) -> void* {
        o = (o + 255) & ~(size_t)255;
        void* p = ws + o;
        o += bytes;
        return p;
    };
    float* bufB = (float*)carve((size_t)NN * 512 * 4);  // GEMM out / feat
    float* bufC = (float*)carve((size_t)NN * 512 * 4);  // agg out
    float* el = (float*)carve((size_t)NN * 8 * 4);
    float* er = (float*)carve((size_t)NN * 8 * 4);
    int* deg = (int*)carve((size_t)NN * 4);
    int* offp = (int*)carve((size_t)(NN + 1) * 4);
    int* cur = (int*)carve((size_t)NN * 4);
    int* csr = (int*)carve((size_t)NE * 4);

    // CSR build
    hipMemsetAsync(deg, 0, (size_t)NN * 4, stream);
    hist_kernel<<<(NE + 255) / 256, 256, 0, stream>>>(dst, deg);
    scan_kernel<<<1, 1024, 0, stream>>>(deg, offp, cur, NN);
    scatter_kernel<<<(NE + 255) / 256, 256, 0, stream>>>(src, dst, cur, csr);

    int gm = (NN + 63) / 64;  // 782
    // ---- layer 1: 256 -> 8x64 ----
    gemm_f32<<<dim3(gm, 8), 256, 0, stream>>>(features, W1, bufB, NN, 512, 256);
    attn_kernel<<<(NN * 8) / 4, 256, 0, stream>>>(bufB, al1, ar1, el, er, 8, 64);
    agg_kernel<<<(NN * 8) / 4, 256, 0, stream>>>(bufB, el, er, offp, csr, bufC, 8, 64);
    // ---- layer 2: 8x64 -> 8x64 ----
    gemm_f32<<<dim3(gm, 8), 256, 0, stream>>>(bufC, W2, bufB, NN, 512, 512);
    attn_kernel<<<(NN * 8) / 4, 256, 0, stream>>>(bufB, al2, ar2, el, er, 8, 64);
    agg_kernel<<<(NN * 8) / 4, 256, 0, stream>>>(bufB, el, er, offp, csr, bufC, 8, 64);
    // ---- layer 3: 8x64 -> 40 ----  (GEMM3 output reuses bufB)
    gemm_f32<<<dim3(gm, 1), 256, 0, stream>>>(bufC, W3, bufB, NN, 40, 512);
    attn_kernel<<<(NN + 3) / 4, 256, 0, stream>>>(bufB, al3, ar3, el, er, 1, 40);
    agg_kernel<<<(NN + 3) / 4, 256, 0, stream>>>(bufB, el, er, offp, csr, (float*)d_out, 1, 40);
}

// Round 4
// 1103.002 us; speedup vs baseline: 1.7674x; 1.7674x over previous
//
#include <hip/hip_runtime.h>
#include <hip/hip_bf16.h>

#define NN 50000
#define NE 400000
#define MPAD 50048  // 391 * 128

typedef __bf16 bf16x8_t __attribute__((ext_vector_type(8)));
typedef float f32x4_t __attribute__((ext_vector_type(4)));

__device__ __forceinline__ float bf2f(__hip_bfloat16 x) { return __bfloat162float(x); }

// ---------- CSR build ----------
__global__ void hist_kernel(const int* __restrict__ dst, int* __restrict__ deg) {
    int e = blockIdx.x * blockDim.x + threadIdx.x;
    if (e < NE) atomicAdd(&deg[dst[e]], 1);
}

__global__ void scan_kernel(const int* __restrict__ deg, int* __restrict__ off,
                            int* __restrict__ cur, int n) {
    __shared__ int sm[1024];
    __shared__ int carry_s;
    if (threadIdx.x == 0) carry_s = 0;
    __syncthreads();
    for (int base = 0; base < n; base += 1024) {
        int i = base + (int)threadIdx.x;
        int v = (i < n) ? deg[i] : 0;
        sm[threadIdx.x] = v;
        __syncthreads();
        for (int o = 1; o < 1024; o <<= 1) {
            int t = (threadIdx.x >= (unsigned)o) ? sm[threadIdx.x - o] : 0;
            __syncthreads();
            sm[threadIdx.x] += t;
            __syncthreads();
        }
        int carry = carry_s;
        int excl = carry + sm[threadIdx.x] - v;
        if (i < n) { off[i] = excl; cur[i] = excl; }
        __syncthreads();
        if (threadIdx.x == 1023) carry_s = carry + sm[1023];
        __syncthreads();
    }
    if (threadIdx.x == 0) off[n] = carry_s;
}

__global__ void scatter_kernel(const int* __restrict__ src, const int* __restrict__ dst,
                               int* __restrict__ cur, int* __restrict__ csr_src) {
    int e = blockIdx.x * blockDim.x + threadIdx.x;
    if (e < NE) {
        int p = atomicAdd(&cur[dst[e]], 1);
        csr_src[p] = src[e];
    }
}

// ---------- casts ----------
__global__ void cast_f2b(const float* __restrict__ in, __hip_bfloat16* __restrict__ out, int n) {
    int i = blockIdx.x * blockDim.x + threadIdx.x;
    if (i < n) out[i] = __float2bfloat16(in[i]);
}

// W [K][Nc] fp32 -> Wt [Nc][K] bf16
__global__ void transpose_cast(const float* __restrict__ W, __hip_bfloat16* __restrict__ Wt,
                               int K, int Nc) {
    int i = blockIdx.x * blockDim.x + threadIdx.x;
    if (i < K * Nc) {
        int k = i / Nc, n = i - k * Nc;
        Wt[(size_t)n * K + k] = __float2bfloat16(W[i]);
    }
}

// ---------- MFMA bf16 GEMM: C[M,Nc](bf16) = A[Mpad,K](bf16) @ Wt[Nc,K](bf16)^T ----------
__device__ __forceinline__ void gld_lds16(const void* g, void* l) {
    __builtin_amdgcn_global_load_lds(
        (const __attribute__((address_space(1))) unsigned int*)g,
        (__attribute__((address_space(3))) unsigned int*)l, 16, 0, 0);
}

__global__ __launch_bounds__(256) void gemm_bt_bf16(const __hip_bfloat16* __restrict__ A,
                                                    const __hip_bfloat16* __restrict__ Wt,
                                                    __hip_bfloat16* __restrict__ C,
                                                    int M, int Nc, int K) {
    __shared__ __align__(16) char smem[16384];  // A tile 8KB | B tile 8KB
    char* smemA = smem;
    char* smemB = smem + 8192;
    const int w = threadIdx.x >> 6;
    const int lane = threadIdx.x & 63;
    const int row0 = blockIdx.x * 128;
    const int col0 = blockIdx.y * 128;
    const int quad = lane >> 4, l15 = lane & 15;
    const int wm = (w >> 1) * 64, wn = (w & 1) * 64;

    // staging: chunk c (1KB) covers tile rows [c*16, c*16+16); lane i deposits 16B at
    // LDS base+i*16 == row i/4, elems (i&3)*8..+8  (row = 32 bf16 = 64B)
    const int c0 = w * 2;
    const int srow = lane >> 2;
    const int skel = (lane & 3) * 8;

    f32x4_t acc[4][4] = {};
    for (int k0 = 0; k0 < K; k0 += 32) {
        __syncthreads();
        {
            const __hip_bfloat16* gA0 = A + (size_t)(row0 + c0 * 16 + srow) * K + k0 + skel;
            const __hip_bfloat16* gB0 = Wt + (size_t)(col0 + c0 * 16 + srow) * K + k0 + skel;
            gld_lds16(gA0, smemA + c0 * 1024);
            gld_lds16(gA0 + (size_t)16 * K, smemA + (c0 + 1) * 1024);
            gld_lds16(gB0, smemB + c0 * 1024);
            gld_lds16(gB0 + (size_t)16 * K, smemB + (c0 + 1) * 1024);
        }
        __syncthreads();
        bf16x8_t a[4], b[4];
#pragma unroll
        for (int mi = 0; mi < 4; mi++)
            a[mi] = *reinterpret_cast<const bf16x8_t*>(smemA + (wm + mi * 16 + l15) * 64 + quad * 16);
#pragma unroll
        for (int ni = 0; ni < 4; ni++)
            b[ni] = *reinterpret_cast<const bf16x8_t*>(smemB + (wn + ni * 16 + l15) * 64 + quad * 16);
#pragma unroll
        for (int mi = 0; mi < 4; mi++)
#pragma unroll
            for (int ni = 0; ni < 4; ni++)
                acc[mi][ni] = __builtin_amdgcn_mfma_f32_16x16x32_bf16(a[mi], b[ni], acc[mi][ni], 0, 0, 0);
    }
#pragma unroll
    for (int mi = 0; mi < 4; mi++) {
#pragma unroll
        for (int ni = 0; ni < 4; ni++) {
#pragma unroll
            for (int r = 0; r < 4; r++) {
                int row = row0 + wm + mi * 16 + quad * 4 + r;
                if (row < M)
                    C[(size_t)row * Nc + col0 + wn + ni * 16 + l15] =
                        __float2bfloat16(acc[mi][ni][r]);
            }
        }
    }
}

// ---------- layer-3 GEMM: C[M,Nc](bf16) = A[M,K](bf16) @ B[K,Nc](f32) ----------
__global__ __launch_bounds__(256) void gemm_b3(const __hip_bfloat16* __restrict__ A,
                                               const float* __restrict__ B,
                                               __hip_bfloat16* __restrict__ C,
                                               int M, int Nc, int K) {
    const int BM = 64, BN = 64, BK = 16, TM = 4, TN = 4;
    __shared__ float As[BK][BM + 1];
    __shared__ float Bs[BK][BN + 1];
    int tx = threadIdx.x % 16, ty = threadIdx.x / 16;
    int row0 = blockIdx.x * BM;
    int col0 = blockIdx.y * BN;
    float acc[TM][TN] = {};
    for (int k0 = 0; k0 < K; k0 += BK) {
        for (int i = threadIdx.x; i < BM * BK; i += 256) {
            int r2 = i / BK, k2 = i % BK;
            float v = (row0 + r2 < M) ? bf2f(A[(size_t)(row0 + r2) * K + k0 + k2]) : 0.f;
            As[k2][r2] = v;
        }
        for (int i = threadIdx.x; i < BK * BN; i += 256) {
            int k2 = i / BN, c2 = i % BN;
            float v = (col0 + c2 < Nc) ? B[(size_t)(k0 + k2) * Nc + col0 + c2] : 0.f;
            Bs[k2][c2] = v;
        }
        __syncthreads();
#pragma unroll
        for (int kk = 0; kk < BK; ++kk) {
            float a[TM], b[TN];
#pragma unroll
            for (int i = 0; i < TM; i++) a[i] = As[kk][ty * TM + i];
#pragma unroll
            for (int j = 0; j < TN; j++) b[j] = Bs[kk][tx * TN + j];
#pragma unroll
            for (int i = 0; i < TM; i++)
#pragma unroll
                for (int j = 0; j < TN; j++) acc[i][j] += a[i] * b[j];
        }
        __syncthreads();
    }
    for (int i = 0; i < TM; i++) {
        int r = row0 + ty * TM + i;
        if (r >= M) continue;
        for (int j = 0; j < TN; j++) {
            int c = col0 + tx * TN + j;
            if (c < Nc) C[(size_t)r * Nc + c] = __float2bfloat16(acc[i][j]);
        }
    }
}

// ---------- attention coefficients (bf16 feat) ----------
__global__ __launch_bounds__(256) void attn_kernel(const __hip_bfloat16* __restrict__ feat,
                                                   const float* __restrict__ al,
                                                   const float* __restrict__ ar,
                                                   float* __restrict__ el, float* __restrict__ er,
                                                   int H, int D) {
    int wid = (blockIdx.x * blockDim.x + threadIdx.x) >> 6;
    int lane = threadIdx.x & 63;
    if (wid >= NN * H) return;
    int n = wid / H, h = wid - n * H;
    float pl = 0.f, pr = 0.f;
    if (lane < D) {
        float v = bf2f(feat[(size_t)n * H * D + h * D + lane]);
        pl = v * al[h * D + lane];
        pr = v * ar[h * D + lane];
    }
    for (int o = 32; o; o >>= 1) {
        pl += __shfl_down(pl, o, 64);
        pr += __shfl_down(pr, o, 64);
    }
    if (lane == 0) { el[wid] = pl; er[wid] = pr; }
}

// ---------- per-(node,head) online-softmax aggregation (bf16 feat) ----------
__global__ __launch_bounds__(256) void agg_kernel(const __hip_bfloat16* __restrict__ feat,
                                                  const float* __restrict__ el,
                                                  const float* __restrict__ er,
                                                  const int* __restrict__ off,
                                                  const int* __restrict__ csr_src,
                                                  float* __restrict__ out_f32,
                                                  __hip_bfloat16* __restrict__ out_bf16,
                                                  int H, int D) {
    int wid = (blockIdx.x * blockDim.x + threadIdx.x) >> 6;
    int lane = threadIdx.x & 63;
    if (wid >= NN * H) return;
    int n = wid / H, h = wid - n * H;
    int rs = off[n], re = off[n + 1];
    float er_n = er[wid];
    float m = -INFINITY, l = 0.f, acc = 0.f;
    for (int base = rs; base < re; base += 64) {
        int cnt = min(64, re - base);
        int s = 0;
        float x = -INFINITY;
        if (lane < cnt) {
            s = csr_src[base + lane];
            float t = el[s * H + h] + er_n;
            x = (t >= 0.f) ? t : 0.2f * t;
        }
        float cm = x;
        for (int o = 32; o; o >>= 1) cm = fmaxf(cm, __shfl_xor(cm, o, 64));
        float nm = fmaxf(m, cm);
        float scale = __expf(m - nm);
        float p = (lane < cnt) ? __expf(x - nm) : 0.f;
        float cl = p;
        for (int o = 32; o; o >>= 1) cl += __shfl_xor(cl, o, 64);
        l = l * scale + cl;
        acc *= scale;
        for (int i = 0; i < cnt; ++i) {
            float pi = __shfl(p, i, 64);
            int si = __shfl(s, i, 64);
            if (lane < D) acc += pi * bf2f(feat[(size_t)si * H * D + h * D + lane]);
        }
        m = nm;
    }
    float res = (l > 0.f) ? acc / l : 0.f;
    if (lane < D) {
        size_t oi = (size_t)n * H * D + h * D + lane;
        if (out_f32) out_f32[oi] = res;
        else out_bf16[oi] = __float2bfloat16(res);
    }
}

extern "C" void kernel_launch(void* const* d_in, const int* in_sizes, int n_in,
                              void* d_out, int out_size, void* d_ws, size_t ws_size,
                              hipStream_t stream) {
    const float* features = (const float*)d_in[0];
    const int* src = (const int*)d_in[1];
    const int* dst = (const int*)d_in[2];
    const float* W1 = (const float*)d_in[3];
    const float* al1 = (const float*)d_in[4];
    const float* ar1 = (const float*)d_in[5];
    const float* W2 = (const float*)d_in[6];
    const float* al2 = (const float*)d_in[7];
    const float* ar2 = (const float*)d_in[8];
    const float* W3 = (const float*)d_in[9];
    const float* al3 = (const float*)d_in[10];
    const float* ar3 = (const float*)d_in[11];

    char* ws = (char*)d_ws;
    size_t o = 0;
    auto carve = [&](size_t bytes) -> void* {
        o = (o + 255) & ~(size_t)255;
        void* p = ws + o;
        o += bytes;
        return p;
    };
    // total ~134 MB (known-safe: 206 MB worked in round 2)
    __hip_bfloat16* Abf1 = (__hip_bfloat16*)carve((size_t)MPAD * 256 * 2);  // features bf16
    __hip_bfloat16* Fbf = (__hip_bfloat16*)carve((size_t)MPAD * 512 * 2);   // gemm out (feat)
    __hip_bfloat16* Gbf = (__hip_bfloat16*)carve((size_t)MPAD * 512 * 2);   // agg out
    __hip_bfloat16* W1t = (__hip_bfloat16*)carve((size_t)512 * 256 * 2);
    __hip_bfloat16* W2t = (__hip_bfloat16*)carve((size_t)512 * 512 * 2);
    float* el = (float*)carve((size_t)NN * 8 * 4);
    float* er = (float*)carve((size_t)NN * 8 * 4);
    int* deg = (int*)carve((size_t)NN * 4);
    int* offp = (int*)carve((size_t)(NN + 1) * 4);
    int* cur = (int*)carve((size_t)NN * 4);
    int* csr = (int*)carve((size_t)NE * 4);

    // CSR build
    hipMemsetAsync(deg, 0, (size_t)NN * 4, stream);
    hist_kernel<<<(NE + 255) / 256, 256, 0, stream>>>(dst, deg);
    scan_kernel<<<1, 1024, 0, stream>>>(deg, offp, cur, NN);
    scatter_kernel<<<(NE + 255) / 256, 256, 0, stream>>>(src, dst, cur, csr);

    // bf16 casts / weight transposes
    cast_f2b<<<(NN * 256 + 255) / 256, 256, 0, stream>>>(features, Abf1, NN * 256);
    transpose_cast<<<(256 * 512 + 255) / 256, 256, 0, stream>>>(W1, W1t, 256, 512);
    transpose_cast<<<(512 * 512 + 255) / 256, 256, 0, stream>>>(W2, W2t, 512, 512);

    const int gmm = MPAD / 128;  // 391
    // ---- layer 1: 256 -> 8x64 ----
    gemm_bt_bf16<<<dim3(gmm, 4), 256, 0, stream>>>(Abf1, W1t, Fbf, NN, 512, 256);
    attn_kernel<<<(NN * 8) / 4, 256, 0, stream>>>(Fbf, al1, ar1, el, er, 8, 64);
    agg_kernel<<<(NN * 8) / 4, 256, 0, stream>>>(Fbf, el, er, offp, csr, nullptr, Gbf, 8, 64);
    // ---- layer 2: 8x64 -> 8x64 ----
    gemm_bt_bf16<<<dim3(gmm, 4), 256, 0, stream>>>(Gbf, W2t, Fbf, NN, 512, 512);
    attn_kernel<<<(NN * 8) / 4, 256, 0, stream>>>(Fbf, al2, ar2, el, er, 8, 64);
    agg_kernel<<<(NN * 8) / 4, 256, 0, stream>>>(Fbf, el, er, offp, csr, nullptr, Gbf, 8, 64);
    // ---- layer 3: 8x64 -> 40 ----
    gemm_b3<<<dim3((NN + 63) / 64, 1), 256, 0, stream>>>(Gbf, W3, Fbf, NN, 40, 512);
    attn_kernel<<<(NN + 3) / 4, 256, 0, stream>>>(Fbf, al3, ar3, el, er, 1, 40);
    agg_kernel<<<(NN + 3) / 4, 256, 0, stream>>>(Fbf, el, er, offp, csr, (float*)d_out, nullptr, 1, 40);
}

// Round 5
// 666.367 us; speedup vs baseline: 2.9255x; 1.6552x over previous
//
#include <hip/hip_runtime.h>
#include <hip/hip_bf16.h>

#define NN 50000
#define NE 400000
#define MPAD 50048  // 391 * 128

typedef __bf16 bf16x8_t __attribute__((ext_vector_type(8)));
typedef float f32x4_t __attribute__((ext_vector_type(4)));

__device__ __forceinline__ float bf2f(__hip_bfloat16 x) { return __bfloat162float(x); }
__device__ __forceinline__ float bfbits2f(unsigned int u) {
    union { unsigned int i; float f; } v;
    v.i = u << 16;
    return v.f;
}
__device__ __forceinline__ void unpack8(uint4 q, float* f) {
    f[0] = bfbits2f(q.x & 0xffffu); f[1] = bfbits2f(q.x >> 16);
    f[2] = bfbits2f(q.y & 0xffffu); f[3] = bfbits2f(q.y >> 16);
    f[4] = bfbits2f(q.z & 0xffffu); f[5] = bfbits2f(q.z >> 16);
    f[6] = bfbits2f(q.w & 0xffffu); f[7] = bfbits2f(q.w >> 16);
}

// ---------- CSR build ----------
__global__ void hist_kernel(const int* __restrict__ dst, int* __restrict__ deg) {
    int e = blockIdx.x * blockDim.x + threadIdx.x;
    if (e < NE) atomicAdd(&deg[dst[e]], 1);
}

__global__ void scan_kernel(const int* __restrict__ deg, int* __restrict__ off,
                            int* __restrict__ cur, int n) {
    __shared__ int sm[1024];
    __shared__ int carry_s;
    if (threadIdx.x == 0) carry_s = 0;
    __syncthreads();
    for (int base = 0; base < n; base += 1024) {
        int i = base + (int)threadIdx.x;
        int v = (i < n) ? deg[i] : 0;
        sm[threadIdx.x] = v;
        __syncthreads();
        for (int o = 1; o < 1024; o <<= 1) {
            int t = (threadIdx.x >= (unsigned)o) ? sm[threadIdx.x - o] : 0;
            __syncthreads();
            sm[threadIdx.x] += t;
            __syncthreads();
        }
        int carry = carry_s;
        int excl = carry + sm[threadIdx.x] - v;
        if (i < n) { off[i] = excl; cur[i] = excl; }
        __syncthreads();
        if (threadIdx.x == 1023) carry_s = carry + sm[1023];
        __syncthreads();
    }
    if (threadIdx.x == 0) off[n] = carry_s;
}

__global__ void scatter_kernel(const int* __restrict__ src, const int* __restrict__ dst,
                               int* __restrict__ cur, int* __restrict__ csr_src) {
    int e = blockIdx.x * blockDim.x + threadIdx.x;
    if (e < NE) {
        int p = atomicAdd(&cur[dst[e]], 1);
        csr_src[p] = src[e];
    }
}

// ---------- casts ----------
__global__ void cast_f2b(const float* __restrict__ in, __hip_bfloat16* __restrict__ out, int n) {
    int i = blockIdx.x * blockDim.x + threadIdx.x;
    if (i < n) out[i] = __float2bfloat16(in[i]);
}

__global__ void transpose_cast(const float* __restrict__ W, __hip_bfloat16* __restrict__ Wt,
                               int K, int Nc) {
    int i = blockIdx.x * blockDim.x + threadIdx.x;
    if (i < K * Nc) {
        int k = i / Nc, n = i - k * Nc;
        Wt[(size_t)n * K + k] = __float2bfloat16(W[i]);
    }
}

// ---------- MFMA bf16 GEMM: C[M,Nc](bf16) = A[Mpad,K](bf16) @ Wt[Nc,K](bf16)^T ----------
__device__ __forceinline__ void gld_lds16(const void* g, void* l) {
    __builtin_amdgcn_global_load_lds(
        (const __attribute__((address_space(1))) unsigned int*)g,
        (__attribute__((address_space(3))) unsigned int*)l, 16, 0, 0);
}

__global__ __launch_bounds__(256) void gemm_bt_bf16(const __hip_bfloat16* __restrict__ A,
                                                    const __hip_bfloat16* __restrict__ Wt,
                                                    __hip_bfloat16* __restrict__ C,
                                                    int M, int Nc, int K) {
    __shared__ __align__(16) char smem[16384];
    char* smemA = smem;
    char* smemB = smem + 8192;
    const int w = threadIdx.x >> 6;
    const int lane = threadIdx.x & 63;
    const int row0 = blockIdx.x * 128;
    const int col0 = blockIdx.y * 128;
    const int quad = lane >> 4, l15 = lane & 15;
    const int wm = (w >> 1) * 64, wn = (w & 1) * 64;
    const int c0 = w * 2;
    const int srow = lane >> 2;
    const int skel = (lane & 3) * 8;

    f32x4_t acc[4][4] = {};
    for (int k0 = 0; k0 < K; k0 += 32) {
        __syncthreads();
        {
            const __hip_bfloat16* gA0 = A + (size_t)(row0 + c0 * 16 + srow) * K + k0 + skel;
            const __hip_bfloat16* gB0 = Wt + (size_t)(col0 + c0 * 16 + srow) * K + k0 + skel;
            gld_lds16(gA0, smemA + c0 * 1024);
            gld_lds16(gA0 + (size_t)16 * K, smemA + (c0 + 1) * 1024);
            gld_lds16(gB0, smemB + c0 * 1024);
            gld_lds16(gB0 + (size_t)16 * K, smemB + (c0 + 1) * 1024);
        }
        __syncthreads();
        bf16x8_t a[4], b[4];
#pragma unroll
        for (int mi = 0; mi < 4; mi++)
            a[mi] = *reinterpret_cast<const bf16x8_t*>(smemA + (wm + mi * 16 + l15) * 64 + quad * 16);
#pragma unroll
        for (int ni = 0; ni < 4; ni++)
            b[ni] = *reinterpret_cast<const bf16x8_t*>(smemB + (wn + ni * 16 + l15) * 64 + quad * 16);
#pragma unroll
        for (int mi = 0; mi < 4; mi++)
#pragma unroll
            for (int ni = 0; ni < 4; ni++)
                acc[mi][ni] = __builtin_amdgcn_mfma_f32_16x16x32_bf16(a[mi], b[ni], acc[mi][ni], 0, 0, 0);
    }
#pragma unroll
    for (int mi = 0; mi < 4; mi++) {
#pragma unroll
        for (int ni = 0; ni < 4; ni++) {
#pragma unroll
            for (int r = 0; r < 4; r++) {
                int row = row0 + wm + mi * 16 + quad * 4 + r;
                if (row < M)
                    C[(size_t)row * Nc + col0 + wn + ni * 16 + l15] =
                        __float2bfloat16(acc[mi][ni][r]);
            }
        }
    }
}

// ---------- layer-3 GEMM: C[M,Nc](bf16) = A[M,K](bf16) @ B[K,Nc](f32) ----------
__global__ __launch_bounds__(256) void gemm_b3(const __hip_bfloat16* __restrict__ A,
                                               const float* __restrict__ B,
                                               __hip_bfloat16* __restrict__ C,
                                               int M, int Nc, int K) {
    const int BM = 64, BN = 64, BK = 16, TM = 4, TN = 4;
    __shared__ float As[BK][BM + 1];
    __shared__ float Bs[BK][BN + 1];
    int tx = threadIdx.x % 16, ty = threadIdx.x / 16;
    int row0 = blockIdx.x * BM;
    int col0 = blockIdx.y * BN;
    float acc[TM][TN] = {};
    for (int k0 = 0; k0 < K; k0 += BK) {
        for (int i = threadIdx.x; i < BM * BK; i += 256) {
            int r2 = i / BK, k2 = i % BK;
            float v = (row0 + r2 < M) ? bf2f(A[(size_t)(row0 + r2) * K + k0 + k2]) : 0.f;
            As[k2][r2] = v;
        }
        for (int i = threadIdx.x; i < BK * BN; i += 256) {
            int k2 = i / BN, c2 = i % BN;
            float v = (col0 + c2 < Nc) ? B[(size_t)(k0 + k2) * Nc + col0 + c2] : 0.f;
            Bs[k2][c2] = v;
        }
        __syncthreads();
#pragma unroll
        for (int kk = 0; kk < BK; ++kk) {
            float a[TM], b[TN];
#pragma unroll
            for (int i = 0; i < TM; i++) a[i] = As[kk][ty * TM + i];
#pragma unroll
            for (int j = 0; j < TN; j++) b[j] = Bs[kk][tx * TN + j];
#pragma unroll
            for (int i = 0; i < TM; i++)
#pragma unroll
                for (int j = 0; j < TN; j++) acc[i][j] += a[i] * b[j];
        }
        __syncthreads();
    }
    for (int i = 0; i < TM; i++) {
        int r = row0 + ty * TM + i;
        if (r >= M) continue;
        for (int j = 0; j < TN; j++) {
            int c = col0 + tx * TN + j;
            if (c < Nc) C[(size_t)r * Nc + c] = __float2bfloat16(acc[i][j]);
        }
    }
}

// ---------- fused attn for H=8,D=64: one wave per node, all heads ----------
// lane covers head lane>>3, d-chunk (lane&7)*8  (al index = lane*8+d)
__global__ __launch_bounds__(256) void attn8_kernel(const __hip_bfloat16* __restrict__ feat,
                                                    const float* __restrict__ al,
                                                    const float* __restrict__ ar,
                                                    float* __restrict__ el,
                                                    float* __restrict__ er) {
    int lane = threadIdx.x & 63;
    int wid = (blockIdx.x * blockDim.x + threadIdx.x) >> 6;
    int nw = (gridDim.x * blockDim.x) >> 6;
    float a[8], r[8];
#pragma unroll
    for (int d = 0; d < 8; ++d) { a[d] = al[lane * 8 + d]; r[d] = ar[lane * 8 + d]; }
    for (int n = wid; n < NN; n += nw) {
        uint4 q = *reinterpret_cast<const uint4*>(feat + (size_t)n * 512 + lane * 8);
        float f[8];
        unpack8(q, f);
        float pl = 0.f, pr = 0.f;
#pragma unroll
        for (int d = 0; d < 8; ++d) { pl += f[d] * a[d]; pr += f[d] * r[d]; }
        pl += __shfl_xor(pl, 1, 64); pr += __shfl_xor(pr, 1, 64);
        pl += __shfl_xor(pl, 2, 64); pr += __shfl_xor(pr, 2, 64);
        pl += __shfl_xor(pl, 4, 64); pr += __shfl_xor(pr, 4, 64);
        if ((lane & 7) == 0) {
            el[n * 8 + (lane >> 3)] = pl;
            er[n * 8 + (lane >> 3)] = pr;
        }
    }
}

// ---------- fused agg for H=8,D=64: one wave per node, all heads ----------
__global__ __launch_bounds__(256) void agg8_kernel(const __hip_bfloat16* __restrict__ feat,
                                                   const float* __restrict__ el,
                                                   const float* __restrict__ er,
                                                   const int* __restrict__ off,
                                                   const int* __restrict__ csr,
                                                   __hip_bfloat16* __restrict__ out) {
    int n = (blockIdx.x * blockDim.x + threadIdx.x) >> 6;
    int lane = threadIdx.x & 63;
    if (n >= NN) return;
    const int h8 = lane & 7;   // head for el/softmax phase
    const int es = lane >> 3;  // edge-slot (0..7)
    const int hd = lane >> 3;  // head for feat phase
    int rs = off[n], re = off[n + 1];
    float er_n = er[n * 8 + h8];

    // Pass A: per-head running max over edges (8 edges at a time)
    float m = -INFINITY;
    for (int base = rs; base < re; base += 8) {
        int e = base + es;
        if (e < re) {
            int s = csr[e];
            float t = el[s * 8 + h8] + er_n;
            float x = (t >= 0.f) ? t : 0.2f * t;
            m = fmaxf(m, x);
        }
    }
    m = fmaxf(m, __shfl_xor(m, 8, 64));
    m = fmaxf(m, __shfl_xor(m, 16, 64));
    m = fmaxf(m, __shfl_xor(m, 32, 64));
    // now lanes with equal (lane&7) hold the max of head lane&7

    // Pass B: exp-weights + weighted feature gather
    float lsum = 0.f;
    float acc[8] = {};
    for (int base = rs; base < re; base += 8) {
        int e = base + es;
        float p = 0.f;
        int s = 0;
        if (e < re) {
            s = csr[e];
            float t = el[s * 8 + h8] + er_n;
            float x = (t >= 0.f) ? t : 0.2f * t;
            p = __expf(x - m);
            lsum += p;
        }
        int cnt = min(8, re - base);
        for (int j = 0; j < cnt; ++j) {
            int sj = __shfl(s, j * 8, 64);
            float pj = __shfl(p, j * 8 + hd, 64);
            uint4 q = *reinterpret_cast<const uint4*>(feat + (size_t)sj * 512 + lane * 8);
            float f[8];
            unpack8(q, f);
#pragma unroll
            for (int d = 0; d < 8; ++d) acc[d] += pj * f[d];
        }
    }
    lsum += __shfl_xor(lsum, 8, 64);
    lsum += __shfl_xor(lsum, 16, 64);
    lsum += __shfl_xor(lsum, 32, 64);
    float lh = __shfl(lsum, hd, 64);  // sum for head hd (held at lane hd, whose lane&7==hd)
    float inv = (lh > 0.f) ? 1.f / lh : 0.f;
    bf16x8_t o8;
#pragma unroll
    for (int d = 0; d < 8; ++d) o8[d] = (__bf16)(acc[d] * inv);
    *reinterpret_cast<bf16x8_t*>(out + (size_t)n * 512 + lane * 8) = o8;
}

// ---------- generic attn (layer 3: H=1, D=40) ----------
__global__ __launch_bounds__(256) void attn_kernel(const __hip_bfloat16* __restrict__ feat,
                                                   const float* __restrict__ al,
                                                   const float* __restrict__ ar,
                                                   float* __restrict__ el, float* __restrict__ er,
                                                   int H, int D) {
    int wid = (blockIdx.x * blockDim.x + threadIdx.x) >> 6;
    int lane = threadIdx.x & 63;
    if (wid >= NN * H) return;
    int n = wid / H, h = wid - n * H;
    float pl = 0.f, pr = 0.f;
    if (lane < D) {
        float v = bf2f(feat[(size_t)n * H * D + h * D + lane]);
        pl = v * al[h * D + lane];
        pr = v * ar[h * D + lane];
    }
    for (int o = 32; o; o >>= 1) {
        pl += __shfl_down(pl, o, 64);
        pr += __shfl_down(pr, o, 64);
    }
    if (lane == 0) { el[wid] = pl; er[wid] = pr; }
}

// ---------- generic agg (layer 3: H=1, D=40, fp32 out) ----------
__global__ __launch_bounds__(256) void agg_kernel(const __hip_bfloat16* __restrict__ feat,
                                                  const float* __restrict__ el,
                                                  const float* __restrict__ er,
                                                  const int* __restrict__ off,
                                                  const int* __restrict__ csr_src,
                                                  float* __restrict__ out_f32,
                                                  int H, int D) {
    int wid = (blockIdx.x * blockDim.x + threadIdx.x) >> 6;
    int lane = threadIdx.x & 63;
    if (wid >= NN * H) return;
    int n = wid / H, h = wid - n * H;
    int rs = off[n], re = off[n + 1];
    float er_n = er[wid];
    float m = -INFINITY, l = 0.f, acc = 0.f;
    for (int base = rs; base < re; base += 64) {
        int cnt = min(64, re - base);
        int s = 0;
        float x = -INFINITY;
        if (lane < cnt) {
            s = csr_src[base + lane];
            float t = el[s * H + h] + er_n;
            x = (t >= 0.f) ? t : 0.2f * t;
        }
        float cm = x;
        for (int o = 32; o; o >>= 1) cm = fmaxf(cm, __shfl_xor(cm, o, 64));
        float nm = fmaxf(m, cm);
        float scale = __expf(m - nm);
        float p = (lane < cnt) ? __expf(x - nm) : 0.f;
        float cl = p;
        for (int o = 32; o; o >>= 1) cl += __shfl_xor(cl, o, 64);
        l = l * scale + cl;
        acc *= scale;
        for (int i = 0; i < cnt; ++i) {
            float pi = __shfl(p, i, 64);
            int si = __shfl(s, i, 64);
            if (lane < D) acc += pi * bf2f(feat[(size_t)si * H * D + h * D + lane]);
        }
        m = nm;
    }
    float res = (l > 0.f) ? acc / l : 0.f;
    if (lane < D) out_f32[(size_t)n * H * D + h * D + lane] = res;
}

extern "C" void kernel_launch(void* const* d_in, const int* in_sizes, int n_in,
                              void* d_out, int out_size, void* d_ws, size_t ws_size,
                              hipStream_t stream) {
    const float* features = (const float*)d_in[0];
    const int* src = (const int*)d_in[1];
    const int* dst = (const int*)d_in[2];
    const float* W1 = (const float*)d_in[3];
    const float* al1 = (const float*)d_in[4];
    const float* ar1 = (const float*)d_in[5];
    const float* W2 = (const float*)d_in[6];
    const float* al2 = (const float*)d_in[7];
    const float* ar2 = (const float*)d_in[8];
    const float* W3 = (const float*)d_in[9];
    const float* al3 = (const float*)d_in[10];
    const float* ar3 = (const float*)d_in[11];

    char* ws = (char*)d_ws;
    size_t o = 0;
    auto carve = [&](size_t bytes) -> void* {
        o = (o + 255) & ~(size_t)255;
        void* p = ws + o;
        o += bytes;
        return p;
    };
    __hip_bfloat16* Abf1 = (__hip_bfloat16*)carve((size_t)MPAD * 256 * 2);
    __hip_bfloat16* Fbf = (__hip_bfloat16*)carve((size_t)MPAD * 512 * 2);
    __hip_bfloat16* Gbf = (__hip_bfloat16*)carve((size_t)MPAD * 512 * 2);
    __hip_bfloat16* W1t = (__hip_bfloat16*)carve((size_t)512 * 256 * 2);
    __hip_bfloat16* W2t = (__hip_bfloat16*)carve((size_t)512 * 512 * 2);
    float* el = (float*)carve((size_t)NN * 8 * 4);
    float* er = (float*)carve((size_t)NN * 8 * 4);
    int* deg = (int*)carve((size_t)NN * 4);
    int* offp = (int*)carve((size_t)(NN + 1) * 4);
    int* cur = (int*)carve((size_t)NN * 4);
    int* csr = (int*)carve((size_t)NE * 4);

    // CSR build
    hipMemsetAsync(deg, 0, (size_t)NN * 4, stream);
    hist_kernel<<<(NE + 255) / 256, 256, 0, stream>>>(dst, deg);
    scan_kernel<<<1, 1024, 0, stream>>>(deg, offp, cur, NN);
    scatter_kernel<<<(NE + 255) / 256, 256, 0, stream>>>(src, dst, cur, csr);

    // bf16 casts / weight transposes
    cast_f2b<<<(NN * 256 + 255) / 256, 256, 0, stream>>>(features, Abf1, NN * 256);
    transpose_cast<<<(256 * 512 + 255) / 256, 256, 0, stream>>>(W1, W1t, 256, 512);
    transpose_cast<<<(512 * 512 + 255) / 256, 256, 0, stream>>>(W2, W2t, 512, 512);

    const int gmm = MPAD / 128;  // 391
    const int aggblk = (NN + 3) / 4;  // 4 waves (nodes) per 256-thr block
    // ---- layer 1: 256 -> 8x64 ----
    gemm_bt_bf16<<<dim3(gmm, 4), 256, 0, stream>>>(Abf1, W1t, Fbf, NN, 512, 256);
    attn8_kernel<<<391, 256, 0, stream>>>(Fbf, al1, ar1, el, er);
    agg8_kernel<<<aggblk, 256, 0, stream>>>(Fbf, el, er, offp, csr, Gbf);
    // ---- layer 2: 8x64 -> 8x64 ----
    gemm_bt_bf16<<<dim3(gmm, 4), 256, 0, stream>>>(Gbf, W2t, Fbf, NN, 512, 512);
    attn8_kernel<<<391, 256, 0, stream>>>(Fbf, al2, ar2, el, er);
    agg8_kernel<<<aggblk, 256, 0, stream>>>(Fbf, el, er, offp, csr, Gbf);
    // ---- layer 3: 8x64 -> 40 ----
    gemm_b3<<<dim3((NN + 63) / 64, 1), 256, 0, stream>>>(Gbf, W3, Fbf, NN, 40, 512);
    attn_kernel<<<(NN + 3) / 4, 256, 0, stream>>>(Fbf, al3, ar3, el, er, 1, 40);
    agg_kernel<<<(NN + 3) / 4, 256, 0, stream>>>(Fbf, el, er, offp, csr, (float*)d_out, 1, 40);
}

// Round 6
// 537.702 us; speedup vs baseline: 3.6255x; 1.2393x over previous
//
#include <hip/hip_runtime.h>
#include <hip/hip_bf16.h>

#define NN 50000
#define NE 400000
#define MPAD 50048  // 391 * 128

typedef __bf16 bf16x8_t __attribute__((ext_vector_type(8)));
typedef float f32x4_t __attribute__((ext_vector_type(4)));

__device__ __forceinline__ float bf2f(__hip_bfloat16 x) { return __bfloat162float(x); }
__device__ __forceinline__ float bfbits2f(unsigned int u) {
    union { unsigned int i; float f; } v;
    v.i = u << 16;
    return v.f;
}
__device__ __forceinline__ void unpack8(uint4 q, float* f) {
    f[0] = bfbits2f(q.x & 0xffffu); f[1] = bfbits2f(q.x >> 16);
    f[2] = bfbits2f(q.y & 0xffffu); f[3] = bfbits2f(q.y >> 16);
    f[4] = bfbits2f(q.z & 0xffffu); f[5] = bfbits2f(q.z >> 16);
    f[6] = bfbits2f(q.w & 0xffffu); f[7] = bfbits2f(q.w >> 16);
}

// ---------- CSR build ----------
__global__ void hist_kernel(const int* __restrict__ dst, int* __restrict__ deg) {
    int e = blockIdx.x * blockDim.x + threadIdx.x;
    if (e < NE) atomicAdd(&deg[dst[e]], 1);
}

// single-block shfl-based scan, 1024 threads
__global__ void scan_kernel(const int* __restrict__ deg, int* __restrict__ off,
                            int* __restrict__ cur, int n) {
    __shared__ int wsum[16];
    __shared__ int carry_s;
    const int tid = threadIdx.x;
    const int lane = tid & 63, wid = tid >> 6;
    if (tid == 0) carry_s = 0;
    __syncthreads();
    for (int base = 0; base < n; base += 1024) {
        int i = base + tid;
        int v = (i < n) ? deg[i] : 0;
        int s = v;
        for (int o = 1; o < 64; o <<= 1) {
            int t = __shfl_up(s, o, 64);
            if (lane >= o) s += t;
        }
        if (lane == 63) wsum[wid] = s;
        __syncthreads();
        if (wid == 0) {
            int ws = (lane < 16) ? wsum[lane] : 0;
            for (int o = 1; o < 16; o <<= 1) {
                int t = __shfl_up(ws, o, 64);
                if (lane >= o) ws += t;
            }
            if (lane < 16) wsum[lane] = ws;  // inclusive wave-total scan
        }
        __syncthreads();
        int wpre = (wid == 0) ? 0 : wsum[wid - 1];
        int carry = carry_s;
        int excl = carry + wpre + s - v;
        if (i < n) { off[i] = excl; cur[i] = excl; }
        __syncthreads();
        if (tid == 1023) carry_s = carry + wsum[15];
        // next-iteration barrier orders carry_s update vs reads
    }
    __syncthreads();
    if (tid == 0) off[n] = carry_s;
}

__global__ void scatter_kernel(const int* __restrict__ src, const int* __restrict__ dst,
                               int* __restrict__ cur, int* __restrict__ csr_src) {
    int e = blockIdx.x * blockDim.x + threadIdx.x;
    if (e < NE) {
        int p = atomicAdd(&cur[dst[e]], 1);
        csr_src[p] = src[e];
    }
}

// ---------- casts ----------
__global__ void cast_f2b(const float* __restrict__ in, __hip_bfloat16* __restrict__ out, int n) {
    int i = blockIdx.x * blockDim.x + threadIdx.x;
    if (i < n) out[i] = __float2bfloat16(in[i]);
}

__global__ void transpose_cast(const float* __restrict__ W, __hip_bfloat16* __restrict__ Wt,
                               int K, int Nc) {
    int i = blockIdx.x * blockDim.x + threadIdx.x;
    if (i < K * Nc) {
        int k = i / Nc, n = i - k * Nc;
        Wt[(size_t)n * K + k] = __float2bfloat16(W[i]);
    }
}

// W3 [512][40] f32 -> W3t [48][512] bf16, rows 40..47 zero
__global__ void prep_w3(const float* __restrict__ W3, __hip_bfloat16* __restrict__ W3t) {
    int i = blockIdx.x * blockDim.x + threadIdx.x;  // i = n*512 + k
    if (i < 48 * 512) {
        int n = i >> 9, k = i & 511;
        float v = (n < 40) ? W3[k * 40 + n] : 0.f;
        W3t[i] = __float2bfloat16(v);
    }
}

// ---------- MFMA bf16 GEMM: C[M,Nc](bf16) = A[Mpad,K](bf16) @ Wt[Nc,K](bf16)^T ----------
__device__ __forceinline__ void gld_lds16(const void* g, void* l) {
    __builtin_amdgcn_global_load_lds(
        (const __attribute__((address_space(1))) unsigned int*)g,
        (__attribute__((address_space(3))) unsigned int*)l, 16, 0, 0);
}

__global__ __launch_bounds__(256) void gemm_bt_bf16(const __hip_bfloat16* __restrict__ A,
                                                    const __hip_bfloat16* __restrict__ Wt,
                                                    __hip_bfloat16* __restrict__ C,
                                                    int M, int Nc, int K) {
    __shared__ __align__(16) char smem[16384];
    char* smemA = smem;
    char* smemB = smem + 8192;
    const int w = threadIdx.x >> 6;
    const int lane = threadIdx.x & 63;
    const int row0 = blockIdx.x * 128;
    const int col0 = blockIdx.y * 128;
    const int quad = lane >> 4, l15 = lane & 15;
    const int wm = (w >> 1) * 64, wn = (w & 1) * 64;
    const int c0 = w * 2;
    const int srow = lane >> 2;
    const int skel = (lane & 3) * 8;

    f32x4_t acc[4][4] = {};
    for (int k0 = 0; k0 < K; k0 += 32) {
        __syncthreads();
        {
            const __hip_bfloat16* gA0 = A + (size_t)(row0 + c0 * 16 + srow) * K + k0 + skel;
            const __hip_bfloat16* gB0 = Wt + (size_t)(col0 + c0 * 16 + srow) * K + k0 + skel;
            gld_lds16(gA0, smemA + c0 * 1024);
            gld_lds16(gA0 + (size_t)16 * K, smemA + (c0 + 1) * 1024);
            gld_lds16(gB0, smemB + c0 * 1024);
            gld_lds16(gB0 + (size_t)16 * K, smemB + (c0 + 1) * 1024);
        }
        __syncthreads();
        bf16x8_t a[4], b[4];
#pragma unroll
        for (int mi = 0; mi < 4; mi++)
            a[mi] = *reinterpret_cast<const bf16x8_t*>(smemA + (wm + mi * 16 + l15) * 64 + quad * 16);
#pragma unroll
        for (int ni = 0; ni < 4; ni++)
            b[ni] = *reinterpret_cast<const bf16x8_t*>(smemB + (wn + ni * 16 + l15) * 64 + quad * 16);
#pragma unroll
        for (int mi = 0; mi < 4; mi++)
#pragma unroll
            for (int ni = 0; ni < 4; ni++)
                acc[mi][ni] = __builtin_amdgcn_mfma_f32_16x16x32_bf16(a[mi], b[ni], acc[mi][ni], 0, 0, 0);
    }
#pragma unroll
    for (int mi = 0; mi < 4; mi++) {
#pragma unroll
        for (int ni = 0; ni < 4; ni++) {
#pragma unroll
            for (int r = 0; r < 4; r++) {
                int row = row0 + wm + mi * 16 + quad * 4 + r;
                if (row < M)
                    C[(size_t)row * Nc + col0 + wn + ni * 16 + l15] =
                        __float2bfloat16(acc[mi][ni][r]);
            }
        }
    }
}

// ---------- layer-3 MFMA GEMM + fused attn: feat3 = A @ W3t^T, el/er from epilogue ----------
// W3t [48][512] staged to LDS (row stride 520 elems = 1040 B, conflict-free b-frags).
// One wave per 16-row strip; 3 col-tiles of 16 (cols 0..47, mask to 40).
#define W3_LDSROW 520
__global__ __launch_bounds__(256) void gemm3_mfma(const __hip_bfloat16* __restrict__ A,
                                                  const __hip_bfloat16* __restrict__ W3t,
                                                  const float* __restrict__ al,
                                                  const float* __restrict__ ar,
                                                  __hip_bfloat16* __restrict__ C,
                                                  float* __restrict__ el,
                                                  float* __restrict__ er) {
    __shared__ __align__(16) __hip_bfloat16 wlds[48 * W3_LDSROW];
    // stage W3t: 48 rows x 512 cols, 16B chunks
    for (int c = threadIdx.x; c < 48 * 64; c += 256) {
        int n = c >> 6, koff = (c & 63) * 8;
        *reinterpret_cast<uint4*>(&wlds[n * W3_LDSROW + koff]) =
            *reinterpret_cast<const uint4*>(W3t + n * 512 + koff);
    }
    __syncthreads();
    const int w = threadIdx.x >> 6;
    const int lane = threadIdx.x & 63;
    const int quad = lane >> 4, l15 = lane & 15;
    const int row0 = blockIdx.x * 64 + w * 16;

    f32x4_t acc[3] = {};
    const __hip_bfloat16* arow = A + (size_t)(row0 + l15) * 512;
#pragma unroll 4
    for (int k0 = 0; k0 < 512; k0 += 32) {
        bf16x8_t a = *reinterpret_cast<const bf16x8_t*>(arow + k0 + quad * 8);
#pragma unroll
        for (int c = 0; c < 3; c++) {
            bf16x8_t b = *reinterpret_cast<const bf16x8_t*>(
                &wlds[(c * 16 + l15) * W3_LDSROW + k0 + quad * 8]);
            acc[c] = __builtin_amdgcn_mfma_f32_16x16x32_bf16(a, b, acc[c], 0, 0, 0);
        }
    }
    // epilogue: write feat3 bf16 + fused el/er (H=1, D=40)
#pragma unroll
    for (int r = 0; r < 4; r++) {
        int row = row0 + quad * 4 + r;
        bool rok = row < NN;
        float pl = 0.f, pr = 0.f;
#pragma unroll
        for (int c = 0; c < 3; c++) {
            int col = c * 16 + l15;
            if (col < 40) {
                float v = acc[c][r];
                if (rok) C[(size_t)row * 40 + col] = __float2bfloat16(v);
                pl += v * al[col];
                pr += v * ar[col];
            }
        }
        pl += __shfl_xor(pl, 1, 64); pr += __shfl_xor(pr, 1, 64);
        pl += __shfl_xor(pl, 2, 64); pr += __shfl_xor(pr, 2, 64);
        pl += __shfl_xor(pl, 4, 64); pr += __shfl_xor(pr, 4, 64);
        pl += __shfl_xor(pl, 8, 64); pr += __shfl_xor(pr, 8, 64);
        if (l15 == 0 && rok) { el[row] = pl; er[row] = pr; }
    }
}

// ---------- fused attn for H=8,D=64 ----------
__global__ __launch_bounds__(256) void attn8_kernel(const __hip_bfloat16* __restrict__ feat,
                                                    const float* __restrict__ al,
                                                    const float* __restrict__ ar,
                                                    float* __restrict__ el,
                                                    float* __restrict__ er) {
    int lane = threadIdx.x & 63;
    int wid = (blockIdx.x * blockDim.x + threadIdx.x) >> 6;
    int nw = (gridDim.x * blockDim.x) >> 6;
    float a[8], r[8];
#pragma unroll
    for (int d = 0; d < 8; ++d) { a[d] = al[lane * 8 + d]; r[d] = ar[lane * 8 + d]; }
    for (int n = wid; n < NN; n += nw) {
        uint4 q = *reinterpret_cast<const uint4*>(feat + (size_t)n * 512 + lane * 8);
        float f[8];
        unpack8(q, f);
        float pl = 0.f, pr = 0.f;
#pragma unroll
        for (int d = 0; d < 8; ++d) { pl += f[d] * a[d]; pr += f[d] * r[d]; }
        pl += __shfl_xor(pl, 1, 64); pr += __shfl_xor(pr, 1, 64);
        pl += __shfl_xor(pl, 2, 64); pr += __shfl_xor(pr, 2, 64);
        pl += __shfl_xor(pl, 4, 64); pr += __shfl_xor(pr, 4, 64);
        if ((lane & 7) == 0) {
            el[n * 8 + (lane >> 3)] = pl;
            er[n * 8 + (lane >> 3)] = pr;
        }
    }
}

// ---------- fused agg for H=8,D=64 ----------
__global__ __launch_bounds__(256) void agg8_kernel(const __hip_bfloat16* __restrict__ feat,
                                                   const float* __restrict__ el,
                                                   const float* __restrict__ er,
                                                   const int* __restrict__ off,
                                                   const int* __restrict__ csr,
                                                   __hip_bfloat16* __restrict__ out) {
    int n = (blockIdx.x * blockDim.x + threadIdx.x) >> 6;
    int lane = threadIdx.x & 63;
    if (n >= NN) return;
    const int h8 = lane & 7;
    const int es = lane >> 3;
    const int hd = lane >> 3;
    int rs = off[n], re = off[n + 1];
    float er_n = er[n * 8 + h8];

    float m = -INFINITY;
    for (int base = rs; base < re; base += 8) {
        int e = base + es;
        if (e < re) {
            int s = csr[e];
            float t = el[s * 8 + h8] + er_n;
            float x = (t >= 0.f) ? t : 0.2f * t;
            m = fmaxf(m, x);
        }
    }
    m = fmaxf(m, __shfl_xor(m, 8, 64));
    m = fmaxf(m, __shfl_xor(m, 16, 64));
    m = fmaxf(m, __shfl_xor(m, 32, 64));

    float lsum = 0.f;
    float acc[8] = {};
    for (int base = rs; base < re; base += 8) {
        int e = base + es;
        float p = 0.f;
        int s = 0;
        if (e < re) {
            s = csr[e];
            float t = el[s * 8 + h8] + er_n;
            float x = (t >= 0.f) ? t : 0.2f * t;
            p = __expf(x - m);
            lsum += p;
        }
        int cnt = min(8, re - base);
        for (int j = 0; j < cnt; ++j) {
            int sj = __shfl(s, j * 8, 64);
            float pj = __shfl(p, j * 8 + hd, 64);
            uint4 q = *reinterpret_cast<const uint4*>(feat + (size_t)sj * 512 + lane * 8);
            float f[8];
            unpack8(q, f);
#pragma unroll
            for (int d = 0; d < 8; ++d) acc[d] += pj * f[d];
        }
    }
    lsum += __shfl_xor(lsum, 8, 64);
    lsum += __shfl_xor(lsum, 16, 64);
    lsum += __shfl_xor(lsum, 32, 64);
    float lh = __shfl(lsum, hd, 64);
    float inv = (lh > 0.f) ? 1.f / lh : 0.f;
    bf16x8_t o8;
#pragma unroll
    for (int d = 0; d < 8; ++d) o8[d] = (__bf16)(acc[d] * inv);
    *reinterpret_cast<bf16x8_t*>(out + (size_t)n * 512 + lane * 8) = o8;
}

// ---------- generic agg (layer 3: H=1, D=40, fp32 out) ----------
__global__ __launch_bounds__(256) void agg_kernel(const __hip_bfloat16* __restrict__ feat,
                                                  const float* __restrict__ el,
                                                  const float* __restrict__ er,
                                                  const int* __restrict__ off,
                                                  const int* __restrict__ csr_src,
                                                  float* __restrict__ out_f32,
                                                  int H, int D) {
    int wid = (blockIdx.x * blockDim.x + threadIdx.x) >> 6;
    int lane = threadIdx.x & 63;
    if (wid >= NN * H) return;
    int n = wid / H, h = wid - n * H;
    int rs = off[n], re = off[n + 1];
    float er_n = er[wid];
    float m = -INFINITY, l = 0.f, acc = 0.f;
    for (int base = rs; base < re; base += 64) {
        int cnt = min(64, re - base);
        int s = 0;
        float x = -INFINITY;
        if (lane < cnt) {
            s = csr_src[base + lane];
            float t = el[s * H + h] + er_n;
            x = (t >= 0.f) ? t : 0.2f * t;
        }
        float cm = x;
        for (int o = 32; o; o >>= 1) cm = fmaxf(cm, __shfl_xor(cm, o, 64));
        float nm = fmaxf(m, cm);
        float scale = __expf(m - nm);
        float p = (lane < cnt) ? __expf(x - nm) : 0.f;
        float cl = p;
        for (int o = 32; o; o >>= 1) cl += __shfl_xor(cl, o, 64);
        l = l * scale + cl;
        acc *= scale;
        for (int i = 0; i < cnt; ++i) {
            float pi = __shfl(p, i, 64);
            int si = __shfl(s, i, 64);
            if (lane < D) acc += pi * bf2f(feat[(size_t)si * H * D + h * D + lane]);
        }
        m = nm;
    }
    float res = (l > 0.f) ? acc / l : 0.f;
    if (lane < D) out_f32[(size_t)n * H * D + h * D + lane] = res;
}

extern "C" void kernel_launch(void* const* d_in, const int* in_sizes, int n_in,
                              void* d_out, int out_size, void* d_ws, size_t ws_size,
                              hipStream_t stream) {
    const float* features = (const float*)d_in[0];
    const int* src = (const int*)d_in[1];
    const int* dst = (const int*)d_in[2];
    const float* W1 = (const float*)d_in[3];
    const float* al1 = (const float*)d_in[4];
    const float* ar1 = (const float*)d_in[5];
    const float* W2 = (const float*)d_in[6];
    const float* al2 = (const float*)d_in[7];
    const float* ar2 = (const float*)d_in[8];
    const float* W3 = (const float*)d_in[9];
    const float* al3 = (const float*)d_in[10];
    const float* ar3 = (const float*)d_in[11];

    char* ws = (char*)d_ws;
    size_t o = 0;
    auto carve = [&](size_t bytes) -> void* {
        o = (o + 255) & ~(size_t)255;
        void* p = ws + o;
        o += bytes;
        return p;
    };
    __hip_bfloat16* Abf1 = (__hip_bfloat16*)carve((size_t)MPAD * 256 * 2);
    __hip_bfloat16* Fbf = (__hip_bfloat16*)carve((size_t)MPAD * 512 * 2);
    __hip_bfloat16* Gbf = (__hip_bfloat16*)carve((size_t)MPAD * 512 * 2);
    __hip_bfloat16* W1t = (__hip_bfloat16*)carve((size_t)512 * 256 * 2);
    __hip_bfloat16* W2t = (__hip_bfloat16*)carve((size_t)512 * 512 * 2);
    __hip_bfloat16* W3t = (__hip_bfloat16*)carve((size_t)48 * 512 * 2);
    float* el = (float*)carve((size_t)NN * 8 * 4);
    float* er = (float*)carve((size_t)NN * 8 * 4);
    int* deg = (int*)carve((size_t)NN * 4);
    int* offp = (int*)carve((size_t)(NN + 1) * 4);
    int* cur = (int*)carve((size_t)NN * 4);
    int* csr = (int*)carve((size_t)NE * 4);

    // CSR build
    hipMemsetAsync(deg, 0, (size_t)NN * 4, stream);
    hist_kernel<<<(NE + 255) / 256, 256, 0, stream>>>(dst, deg);
    scan_kernel<<<1, 1024, 0, stream>>>(deg, offp, cur, NN);
    scatter_kernel<<<(NE + 255) / 256, 256, 0, stream>>>(src, dst, cur, csr);

    // bf16 casts / weight transposes
    cast_f2b<<<(NN * 256 + 255) / 256, 256, 0, stream>>>(features, Abf1, NN * 256);
    transpose_cast<<<(256 * 512 + 255) / 256, 256, 0, stream>>>(W1, W1t, 256, 512);
    transpose_cast<<<(512 * 512 + 255) / 256, 256, 0, stream>>>(W2, W2t, 512, 512);
    prep_w3<<<(48 * 512 + 255) / 256, 256, 0, stream>>>(W3, W3t);

    const int gmm = MPAD / 128;  // 391
    const int aggblk = (NN + 3) / 4;
    // ---- layer 1: 256 -> 8x64 ----
    gemm_bt_bf16<<<dim3(gmm, 4), 256, 0, stream>>>(Abf1, W1t, Fbf, NN, 512, 256);
    attn8_kernel<<<391, 256, 0, stream>>>(Fbf, al1, ar1, el, er);
    agg8_kernel<<<aggblk, 256, 0, stream>>>(Fbf, el, er, offp, csr, Gbf);
    // ---- layer 2: 8x64 -> 8x64 ----
    gemm_bt_bf16<<<dim3(gmm, 4), 256, 0, stream>>>(Gbf, W2t, Fbf, NN, 512, 512);
    attn8_kernel<<<391, 256, 0, stream>>>(Fbf, al2, ar2, el, er);
    agg8_kernel<<<aggblk, 256, 0, stream>>>(Fbf, el, er, offp, csr, Gbf);
    // ---- layer 3: 8x64 -> 40, attn fused into GEMM epilogue ----
    gemm3_mfma<<<MPAD / 64, 256, 0, stream>>>(Gbf, W3t, al3, ar3, Fbf, el, er);
    agg_kernel<<<(NN + 3) / 4, 256, 0, stream>>>(Fbf, el, er, offp, csr, (float*)d_out, 1, 40);
}

// Round 7
// 486.043 us; speedup vs baseline: 4.0108x; 1.1063x over previous
//
#include <hip/hip_runtime.h>
#include <hip/hip_bf16.h>

#define NN 50000
#define NE 400000
#define MPAD 50048  // 391 * 128

typedef __bf16 bf16x8_t __attribute__((ext_vector_type(8)));
typedef float f32x4_t __attribute__((ext_vector_type(4)));

__device__ __forceinline__ float bfbits2f(unsigned int u) {
    union { unsigned int i; float f; } v;
    v.i = u << 16;
    return v.f;
}
__device__ __forceinline__ void unpack8(uint4 q, float* f) {
    f[0] = bfbits2f(q.x & 0xffffu); f[1] = bfbits2f(q.x >> 16);
    f[2] = bfbits2f(q.y & 0xffffu); f[3] = bfbits2f(q.y >> 16);
    f[4] = bfbits2f(q.z & 0xffffu); f[5] = bfbits2f(q.z >> 16);
    f[6] = bfbits2f(q.w & 0xffffu); f[7] = bfbits2f(q.w >> 16);
}

// ---------- fused prep: feature cast + degree hist + weight transposes ----------
__global__ __launch_bounds__(256) void prep_kernel(
    const float* __restrict__ features, __hip_bfloat16* __restrict__ Abf,
    const int* __restrict__ dst, int* __restrict__ deg,
    const float* __restrict__ W1, __hip_bfloat16* __restrict__ W1t,
    const float* __restrict__ W2, __hip_bfloat16* __restrict__ W2t,
    const float* __restrict__ W3, __hip_bfloat16* __restrict__ W3t) {
    int stride = gridDim.x * blockDim.x;
    for (int i = blockIdx.x * blockDim.x + threadIdx.x; i < NN * 256; i += stride) {
        Abf[i] = __float2bfloat16(features[i]);
        if (i < NE) atomicAdd(&deg[dst[i]], 1);
        if (i < 512 * 256) {  // W1t [512][256] <- W1 [256][512]
            int n = i >> 8, k = i & 255;
            W1t[i] = __float2bfloat16(W1[k * 512 + n]);
        }
        if (i < 512 * 512) {  // W2t [512][512] <- W2 [512][512]
            int n = i >> 9, k = i & 511;
            W2t[i] = __float2bfloat16(W2[k * 512 + n]);
        }
        if (i < 48 * 512) {   // W3t [48][512] <- W3 [512][40], rows 40..47 zero
            int n = i >> 9, k = i & 511;
            W3t[i] = __float2bfloat16((n < 40) ? W3[k * 40 + n] : 0.f);
        }
    }
}

// ---------- single-block shfl scan ----------
__global__ void scan_kernel(const int* __restrict__ deg, int* __restrict__ off,
                            int* __restrict__ cur, int n) {
    __shared__ int wsum[16];
    __shared__ int carry_s;
    const int tid = threadIdx.x;
    const int lane = tid & 63, wid = tid >> 6;
    if (tid == 0) carry_s = 0;
    __syncthreads();
    for (int base = 0; base < n; base += 1024) {
        int i = base + tid;
        int v = (i < n) ? deg[i] : 0;
        int s = v;
        for (int o = 1; o < 64; o <<= 1) {
            int t = __shfl_up(s, o, 64);
            if (lane >= o) s += t;
        }
        if (lane == 63) wsum[wid] = s;
        __syncthreads();
        if (wid == 0) {
            int ws = (lane < 16) ? wsum[lane] : 0;
            for (int o = 1; o < 16; o <<= 1) {
                int t = __shfl_up(ws, o, 64);
                if (lane >= o) ws += t;
            }
            if (lane < 16) wsum[lane] = ws;
        }
        __syncthreads();
        int wpre = (wid == 0) ? 0 : wsum[wid - 1];
        int carry = carry_s;
        int excl = carry + wpre + s - v;
        if (i < n) { off[i] = excl; cur[i] = excl; }
        __syncthreads();
        if (tid == 1023) carry_s = carry + wsum[15];
    }
    __syncthreads();
    if (tid == 0) off[n] = carry_s;
}

__global__ void scatter_kernel(const int* __restrict__ src, const int* __restrict__ dst,
                               int* __restrict__ cur, int* __restrict__ csr_src) {
    int e = blockIdx.x * blockDim.x + threadIdx.x;
    if (e < NE) {
        int p = atomicAdd(&cur[dst[e]], 1);
        csr_src[p] = src[e];
    }
}

// ---------- MFMA bf16 GEMM + fused attn (layers 1-2, Nc=512, H=8, D=64) ----------
// Each wave covers 64 rows x 64 cols = one full head -> el/er full dot, plain store.
__device__ __forceinline__ void gld_lds16(const void* g, void* l) {
    __builtin_amdgcn_global_load_lds(
        (const __attribute__((address_space(1))) unsigned int*)g,
        (__attribute__((address_space(3))) unsigned int*)l, 16, 0, 0);
}

__global__ __launch_bounds__(256) void gemm_bt_fused(const __hip_bfloat16* __restrict__ A,
                                                     const __hip_bfloat16* __restrict__ Wt,
                                                     const float* __restrict__ al,
                                                     const float* __restrict__ ar,
                                                     __hip_bfloat16* __restrict__ C,
                                                     float* __restrict__ el,
                                                     float* __restrict__ er,
                                                     int K) {
    __shared__ __align__(16) char smem[16384];
    char* smemA = smem;
    char* smemB = smem + 8192;
    const int w = threadIdx.x >> 6;
    const int lane = threadIdx.x & 63;
    const int row0 = blockIdx.x * 128;
    const int col0 = blockIdx.y * 128;
    const int quad = lane >> 4, l15 = lane & 15;
    const int wm = (w >> 1) * 64, wn = (w & 1) * 64;
    const int c0 = w * 2;
    const int srow = lane >> 2;
    const int skel = (lane & 3) * 8;
    const int h = 2 * blockIdx.y + (w & 1);  // head this wave owns

    float alv[4], arv[4];
#pragma unroll
    for (int ni = 0; ni < 4; ni++) {
        alv[ni] = al[h * 64 + ni * 16 + l15];
        arv[ni] = ar[h * 64 + ni * 16 + l15];
    }

    f32x4_t acc[4][4] = {};
    for (int k0 = 0; k0 < K; k0 += 32) {
        __syncthreads();
        {
            const __hip_bfloat16* gA0 = A + (size_t)(row0 + c0 * 16 + srow) * K + k0 + skel;
            const __hip_bfloat16* gB0 = Wt + (size_t)(col0 + c0 * 16 + srow) * K + k0 + skel;
            gld_lds16(gA0, smemA + c0 * 1024);
            gld_lds16(gA0 + (size_t)16 * K, smemA + (c0 + 1) * 1024);
            gld_lds16(gB0, smemB + c0 * 1024);
            gld_lds16(gB0 + (size_t)16 * K, smemB + (c0 + 1) * 1024);
        }
        __syncthreads();
        bf16x8_t a[4], b[4];
#pragma unroll
        for (int mi = 0; mi < 4; mi++)
            a[mi] = *reinterpret_cast<const bf16x8_t*>(smemA + (wm + mi * 16 + l15) * 64 + quad * 16);
#pragma unroll
        for (int ni = 0; ni < 4; ni++)
            b[ni] = *reinterpret_cast<const bf16x8_t*>(smemB + (wn + ni * 16 + l15) * 64 + quad * 16);
#pragma unroll
        for (int mi = 0; mi < 4; mi++)
#pragma unroll
            for (int ni = 0; ni < 4; ni++)
                acc[mi][ni] = __builtin_amdgcn_mfma_f32_16x16x32_bf16(a[mi], b[ni], acc[mi][ni], 0, 0, 0);
    }
    // epilogue: store C + fused el/er (full 64-col dot per head in-wave)
#pragma unroll
    for (int mi = 0; mi < 4; mi++) {
#pragma unroll
        for (int r = 0; r < 4; r++) {
            int row = row0 + wm + mi * 16 + quad * 4 + r;
            bool rok = row < NN;
            float pl = 0.f, pr = 0.f;
#pragma unroll
            for (int ni = 0; ni < 4; ni++) {
                float v = acc[mi][ni][r];
                if (rok)
                    C[(size_t)row * 512 + col0 + wn + ni * 16 + l15] = __float2bfloat16(v);
                pl += v * alv[ni];
                pr += v * arv[ni];
            }
            pl += __shfl_xor(pl, 1, 64); pr += __shfl_xor(pr, 1, 64);
            pl += __shfl_xor(pl, 2, 64); pr += __shfl_xor(pr, 2, 64);
            pl += __shfl_xor(pl, 4, 64); pr += __shfl_xor(pr, 4, 64);
            pl += __shfl_xor(pl, 8, 64); pr += __shfl_xor(pr, 8, 64);
            if (l15 == 0 && rok) {
                el[row * 8 + h] = pl;
                er[row * 8 + h] = pr;
            }
        }
    }
}

// ---------- layer-3 MFMA GEMM + fused attn; C padded to 64 cols ----------
#define W3_LDSROW 520
__global__ __launch_bounds__(256) void gemm3_mfma(const __hip_bfloat16* __restrict__ A,
                                                  const __hip_bfloat16* __restrict__ W3t,
                                                  const float* __restrict__ al,
                                                  const float* __restrict__ ar,
                                                  __hip_bfloat16* __restrict__ C,
                                                  float* __restrict__ el,
                                                  float* __restrict__ er) {
    __shared__ __align__(16) __hip_bfloat16 wlds[48 * W3_LDSROW];
    for (int c = threadIdx.x; c < 48 * 64; c += 256) {
        int n = c >> 6, koff = (c & 63) * 8;
        *reinterpret_cast<uint4*>(&wlds[n * W3_LDSROW + koff]) =
            *reinterpret_cast<const uint4*>(W3t + n * 512 + koff);
    }
    __syncthreads();
    const int w = threadIdx.x >> 6;
    const int lane = threadIdx.x & 63;
    const int quad = lane >> 4, l15 = lane & 15;
    const int row0 = blockIdx.x * 64 + w * 16;

    float alv[3], arv[3];
#pragma unroll
    for (int c = 0; c < 3; c++) {
        int col = c * 16 + l15;
        alv[c] = (col < 40) ? al[col] : 0.f;
        arv[c] = (col < 40) ? ar[col] : 0.f;
    }

    f32x4_t acc[3] = {};
    const __hip_bfloat16* arow = A + (size_t)(row0 + l15) * 512;
#pragma unroll 4
    for (int k0 = 0; k0 < 512; k0 += 32) {
        bf16x8_t a = *reinterpret_cast<const bf16x8_t*>(arow + k0 + quad * 8);
#pragma unroll
        for (int c = 0; c < 3; c++) {
            bf16x8_t b = *reinterpret_cast<const bf16x8_t*>(
                &wlds[(c * 16 + l15) * W3_LDSROW + k0 + quad * 8]);
            acc[c] = __builtin_amdgcn_mfma_f32_16x16x32_bf16(a, b, acc[c], 0, 0, 0);
        }
    }
#pragma unroll
    for (int r = 0; r < 4; r++) {
        int row = row0 + quad * 4 + r;
        bool rok = row < NN;
        float pl = 0.f, pr = 0.f;
#pragma unroll
        for (int c = 0; c < 3; c++) {
            float v = acc[c][r];
            if (rok) C[(size_t)row * 64 + c * 16 + l15] = __float2bfloat16(v);
            pl += v * alv[c];
            pr += v * arv[c];
        }
        if (rok) C[(size_t)row * 64 + 48 + l15] = __float2bfloat16(0.f);
        pl += __shfl_xor(pl, 1, 64); pr += __shfl_xor(pr, 1, 64);
        pl += __shfl_xor(pl, 2, 64); pr += __shfl_xor(pr, 2, 64);
        pl += __shfl_xor(pl, 4, 64); pr += __shfl_xor(pr, 4, 64);
        pl += __shfl_xor(pl, 8, 64); pr += __shfl_xor(pr, 8, 64);
        if (l15 == 0 && rok) { el[row] = pl; er[row] = pr; }
    }
}

// ---------- agg layers 1-2: one wave/node, single-pass online softmax, unrolled gather ----------
__global__ __launch_bounds__(256) void agg8_kernel(const __hip_bfloat16* __restrict__ feat,
                                                   const float* __restrict__ el,
                                                   const float* __restrict__ er,
                                                   const int* __restrict__ off,
                                                   const int* __restrict__ csr,
                                                   __hip_bfloat16* __restrict__ out) {
    int n = (blockIdx.x * blockDim.x + threadIdx.x) >> 6;
    int lane = threadIdx.x & 63;
    if (n >= NN) return;
    const int h8 = lane & 7;   // head (softmax space)
    const int es = lane >> 3;  // edge slot (softmax space)
    const int hd = lane >> 3;  // head (feature space: lane*8 covers head lane>>3)
    int rs = off[n], re = off[n + 1];
    float er_n = er[n * 8 + h8];

    float m = -INFINITY, lsum = 0.f;
    float acc[8] = {};
    for (int base = rs; base < re; base += 8) {
        int e = base + es;
        bool valid = e < re;
        int s = valid ? csr[e] : 0;
        float t = el[s * 8 + h8] + er_n;
        float x = (t >= 0.f) ? t : 0.2f * t;
        if (!valid) x = -INFINITY;
        float gm = x;
        gm = fmaxf(gm, __shfl_xor(gm, 8, 64));
        gm = fmaxf(gm, __shfl_xor(gm, 16, 64));
        gm = fmaxf(gm, __shfl_xor(gm, 32, 64));
        float nm = fmaxf(m, gm);
        float scale = __expf(m - nm);  // first iter: exp(-inf)=0
        float p = __expf(x - nm);      // invalid: 0
        lsum = lsum * scale + p;
        float sc = __shfl(scale, hd, 64);  // head hd's scale (lane hd has h8==hd)
#pragma unroll
        for (int d = 0; d < 8; ++d) acc[d] *= sc;
#pragma unroll
        for (int j = 0; j < 8; ++j) {
            int sj = __shfl(s, j * 8, 64);
            float pj = __shfl(p, j * 8 + hd, 64);
            uint4 q = *reinterpret_cast<const uint4*>(feat + (size_t)sj * 512 + lane * 8);
            float f[8];
            unpack8(q, f);
#pragma unroll
            for (int d = 0; d < 8; ++d) acc[d] += pj * f[d];
        }
        m = nm;
    }
    lsum += __shfl_xor(lsum, 8, 64);
    lsum += __shfl_xor(lsum, 16, 64);
    lsum += __shfl_xor(lsum, 32, 64);
    float lh = __shfl(lsum, hd, 64);
    float inv = (lh > 0.f) ? 1.f / lh : 0.f;
    bf16x8_t o8;
#pragma unroll
    for (int d = 0; d < 8; ++d) o8[d] = (__bf16)(acc[d] * inv);
    *reinterpret_cast<bf16x8_t*>(out + (size_t)n * 512 + lane * 8) = o8;
}

// ---------- agg layer 3: H=1, feat padded to 64 cols; 8 edges per load ----------
__global__ __launch_bounds__(256) void agg3_kernel(const __hip_bfloat16* __restrict__ feat,
                                                   const float* __restrict__ el,
                                                   const float* __restrict__ er,
                                                   const int* __restrict__ off,
                                                   const int* __restrict__ csr,
                                                   float* __restrict__ out) {
    int n = (blockIdx.x * blockDim.x + threadIdx.x) >> 6;
    int lane = threadIdx.x & 63;
    if (n >= NN) return;
    const int es = lane >> 3;  // edge slot
    const int dc = lane & 7;   // 8-elem chunk of the 64-col row
    int rs = off[n], re = off[n + 1];
    float er_n = er[n];

    float m = -INFINITY, lsum = 0.f;
    float acc[8] = {};
    for (int base = rs; base < re; base += 8) {
        int e = base + es;
        bool valid = e < re;
        int s = valid ? csr[e] : 0;
        float t = el[s] + er_n;
        float x = (t >= 0.f) ? t : 0.2f * t;
        if (!valid) x = -INFINITY;
        float gm = x;
        gm = fmaxf(gm, __shfl_xor(gm, 8, 64));
        gm = fmaxf(gm, __shfl_xor(gm, 16, 64));
        gm = fmaxf(gm, __shfl_xor(gm, 32, 64));
        float nm = fmaxf(m, gm);
        float scale = __expf(m - nm);
        float p = __expf(x - nm);
        lsum = lsum * scale + p;
        uint4 q = *reinterpret_cast<const uint4*>(feat + (size_t)s * 64 + dc * 8);
        float f[8];
        unpack8(q, f);
#pragma unroll
        for (int d = 0; d < 8; ++d) acc[d] = acc[d] * scale + p * f[d];
        m = nm;
    }
    lsum += __shfl_xor(lsum, 8, 64);
    lsum += __shfl_xor(lsum, 16, 64);
    lsum += __shfl_xor(lsum, 32, 64);
#pragma unroll
    for (int d = 0; d < 8; ++d) {
        acc[d] += __shfl_xor(acc[d], 8, 64);
        acc[d] += __shfl_xor(acc[d], 16, 64);
        acc[d] += __shfl_xor(acc[d], 32, 64);
    }
    float inv = (lsum > 0.f) ? 1.f / lsum : 0.f;
    if (es == 0 && dc < 5) {
        float4 o0 = make_float4(acc[0] * inv, acc[1] * inv, acc[2] * inv, acc[3] * inv);
        float4 o1 = make_float4(acc[4] * inv, acc[5] * inv, acc[6] * inv, acc[7] * inv);
        *reinterpret_cast<float4*>(out + (size_t)n * 40 + dc * 8) = o0;
        *reinterpret_cast<float4*>(out + (size_t)n * 40 + dc * 8 + 4) = o1;
    }
}

extern "C" void kernel_launch(void* const* d_in, const int* in_sizes, int n_in,
                              void* d_out, int out_size, void* d_ws, size_t ws_size,
                              hipStream_t stream) {
    const float* features = (const float*)d_in[0];
    const int* src = (const int*)d_in[1];
    const int* dst = (const int*)d_in[2];
    const float* W1 = (const float*)d_in[3];
    const float* al1 = (const float*)d_in[4];
    const float* ar1 = (const float*)d_in[5];
    const float* W2 = (const float*)d_in[6];
    const float* al2 = (const float*)d_in[7];
    const float* ar2 = (const float*)d_in[8];
    const float* W3 = (const float*)d_in[9];
    const float* al3 = (const float*)d_in[10];
    const float* ar3 = (const float*)d_in[11];

    char* ws = (char*)d_ws;
    size_t o = 0;
    auto carve = [&](size_t bytes) -> void* {
        o = (o + 255) & ~(size_t)255;
        void* p = ws + o;
        o += bytes;
        return p;
    };
    __hip_bfloat16* Abf1 = (__hip_bfloat16*)carve((size_t)MPAD * 256 * 2);
    __hip_bfloat16* Fbf = (__hip_bfloat16*)carve((size_t)MPAD * 512 * 2);
    __hip_bfloat16* Gbf = (__hip_bfloat16*)carve((size_t)MPAD * 512 * 2);
    __hip_bfloat16* W1t = (__hip_bfloat16*)carve((size_t)512 * 256 * 2);
    __hip_bfloat16* W2t = (__hip_bfloat16*)carve((size_t)512 * 512 * 2);
    __hip_bfloat16* W3t = (__hip_bfloat16*)carve((size_t)48 * 512 * 2);
    float* el = (float*)carve((size_t)NN * 8 * 4);
    float* er = (float*)carve((size_t)NN * 8 * 4);
    float* el3 = (float*)carve((size_t)NN * 4);
    float* er3 = (float*)carve((size_t)NN * 4);
    int* deg = (int*)carve((size_t)NN * 4);
    int* offp = (int*)carve((size_t)(NN + 1) * 4);
    int* cur = (int*)carve((size_t)NN * 4);
    int* csr = (int*)carve((size_t)NE * 4);

    hipMemsetAsync(deg, 0, (size_t)NN * 4, stream);
    prep_kernel<<<4096, 256, 0, stream>>>(features, Abf1, dst, deg, W1, W1t, W2, W2t, W3, W3t);
    scan_kernel<<<1, 1024, 0, stream>>>(deg, offp, cur, NN);
    scatter_kernel<<<(NE + 255) / 256, 256, 0, stream>>>(src, dst, cur, csr);

    const int gmm = MPAD / 128;       // 391
    const int aggblk = (NN + 3) / 4;  // 12500
    // ---- layer 1 ----
    gemm_bt_fused<<<dim3(gmm, 4), 256, 0, stream>>>(Abf1, W1t, al1, ar1, Fbf, el, er, 256);
    agg8_kernel<<<aggblk, 256, 0, stream>>>(Fbf, el, er, offp, csr, Gbf);
    // ---- layer 2 ----
    gemm_bt_fused<<<dim3(gmm, 4), 256, 0, stream>>>(Gbf, W2t, al2, ar2, Fbf, el, er, 512);
    agg8_kernel<<<aggblk, 256, 0, stream>>>(Fbf, el, er, offp, csr, Gbf);
    // ---- layer 3 (feat padded to 64 cols in Fbf) ----
    gemm3_mfma<<<MPAD / 64, 256, 0, stream>>>(Gbf, W3t, al3, ar3, Fbf, el3, er3);
    agg3_kernel<<<aggblk, 256, 0, stream>>>(Fbf, el3, er3, offp, csr, (float*)d_out);
}

// Round 8
// 482.182 us; speedup vs baseline: 4.0430x; 1.0080x over previous
//
#include <hip/hip_runtime.h>
#include <hip/hip_bf16.h>

#define NN 50000
#define NE 400000
#define MPAD 50048  // 391 * 128

typedef __bf16 bf16x8_t __attribute__((ext_vector_type(8)));
typedef float f32x4_t __attribute__((ext_vector_type(4)));

__device__ __forceinline__ float bfbits2f(unsigned int u) {
    union { unsigned int i; float f; } v;
    v.i = u << 16;
    return v.f;
}
__device__ __forceinline__ void unpack8(uint4 q, float* f) {
    f[0] = bfbits2f(q.x & 0xffffu); f[1] = bfbits2f(q.x >> 16);
    f[2] = bfbits2f(q.y & 0xffffu); f[3] = bfbits2f(q.y >> 16);
    f[4] = bfbits2f(q.z & 0xffffu); f[5] = bfbits2f(q.z >> 16);
    f[6] = bfbits2f(q.w & 0xffffu); f[7] = bfbits2f(q.w >> 16);
}

// ---------- fused prep: feature cast + hist + weight transposes + wal/war tables ----------
// walr layout (MFMA chunk format): elem (chunk c, j, kk) at c*512 + j*32 + kk,
// j<8 -> W^T al head j ; j>=8 -> W^T ar head j-8 ; k = c*32+kk.
__global__ __launch_bounds__(256) void prep_kernel(
    const float* __restrict__ features, __hip_bfloat16* __restrict__ Abf,
    const int* __restrict__ dst, int* __restrict__ deg,
    const float* __restrict__ W1, __hip_bfloat16* __restrict__ W1t,
    const float* __restrict__ W2, __hip_bfloat16* __restrict__ W2t,
    const float* __restrict__ W3, __hip_bfloat16* __restrict__ W3t,
    const float* __restrict__ al1, const float* __restrict__ ar1,
    const float* __restrict__ al2, const float* __restrict__ ar2,
    __hip_bfloat16* __restrict__ walr1, __hip_bfloat16* __restrict__ walr2) {
    int stride = gridDim.x * blockDim.x;
    for (int i = blockIdx.x * blockDim.x + threadIdx.x; i < NN * 256; i += stride) {
        Abf[i] = __float2bfloat16(features[i]);
        if (i < NE) atomicAdd(&deg[dst[i]], 1);
        if (i < 512 * 256) {  // W1t [512][256] <- W1 [256][512]
            int n = i >> 8, k = i & 255;
            W1t[i] = __float2bfloat16(W1[k * 512 + n]);
        }
        if (i < 512 * 512) {  // W2t [512][512] <- W2 [512][512]
            int n = i >> 9, k = i & 511;
            W2t[i] = __float2bfloat16(W2[k * 512 + n]);
        }
        if (i < 48 * 512) {   // W3t [48][512] <- W3 [512][40], rows 40..47 zero
            int n = i >> 9, k = i & 511;
            W3t[i] = __float2bfloat16((n < 40) ? W3[k * 40 + n] : 0.f);
        }
        if (i < 16 * 256) {   // walr1: K=256
            int j = i >> 8, k = i & 255;
            const float* v = (j < 8) ? (al1 + j * 64) : (ar1 + (j - 8) * 64);
            float s = 0.f;
            for (int d = 0; d < 64; ++d) s += W1[(size_t)k * 512 + (j & 7) * 64 + d] * v[d];
            walr1[(k >> 5) * 512 + j * 32 + (k & 31)] = __float2bfloat16(s);
        }
        if (i < 16 * 512) {   // walr2: K=512
            int j = i >> 9, k = i & 511;
            const float* v = (j < 8) ? (al2 + j * 64) : (ar2 + (j - 8) * 64);
            float s = 0.f;
            for (int d = 0; d < 64; ++d) s += W2[(size_t)k * 512 + (j & 7) * 64 + d] * v[d];
            walr2[(k >> 5) * 512 + j * 32 + (k & 31)] = __float2bfloat16(s);
        }
    }
}

// ---------- single-block shfl scan ----------
__global__ void scan_kernel(const int* __restrict__ deg, int* __restrict__ off,
                            int* __restrict__ cur, int n) {
    __shared__ int wsum[16];
    __shared__ int carry_s;
    const int tid = threadIdx.x;
    const int lane = tid & 63, wid = tid >> 6;
    if (tid == 0) carry_s = 0;
    __syncthreads();
    for (int base = 0; base < n; base += 1024) {
        int i = base + tid;
        int v = (i < n) ? deg[i] : 0;
        int s = v;
        for (int o = 1; o < 64; o <<= 1) {
            int t = __shfl_up(s, o, 64);
            if (lane >= o) s += t;
        }
        if (lane == 63) wsum[wid] = s;
        __syncthreads();
        if (wid == 0) {
            int ws = (lane < 16) ? wsum[lane] : 0;
            for (int o = 1; o < 16; o <<= 1) {
                int t = __shfl_up(ws, o, 64);
                if (lane >= o) ws += t;
            }
            if (lane < 16) wsum[lane] = ws;
        }
        __syncthreads();
        int wpre = (wid == 0) ? 0 : wsum[wid - 1];
        int carry = carry_s;
        int excl = carry + wpre + s - v;
        if (i < n) { off[i] = excl; cur[i] = excl; }
        __syncthreads();
        if (tid == 1023) carry_s = carry + wsum[15];
    }
    __syncthreads();
    if (tid == 0) off[n] = carry_s;
}

__global__ void scatter_kernel(const int* __restrict__ src, const int* __restrict__ dst,
                               int* __restrict__ cur, int* __restrict__ csr_src) {
    int e = blockIdx.x * blockDim.x + threadIdx.x;
    if (e < NE) {
        int p = atomicAdd(&cur[dst[e]], 1);
        csr_src[p] = src[e];
    }
}

// ---------- MFMA bf16 GEMM + MFMA-fused el/er (layers 1-2) ----------
__device__ __forceinline__ void gld_lds16(const void* g, void* l) {
    __builtin_amdgcn_global_load_lds(
        (const __attribute__((address_space(1))) unsigned int*)g,
        (__attribute__((address_space(3))) unsigned int*)l, 16, 0, 0);
}

__global__ __launch_bounds__(256) void gemm_bt_fused(const __hip_bfloat16* __restrict__ A,
                                                     const __hip_bfloat16* __restrict__ Wt,
                                                     const __hip_bfloat16* __restrict__ walr,
                                                     __hip_bfloat16* __restrict__ C,
                                                     float* __restrict__ el,
                                                     float* __restrict__ er,
                                                     int K) {
    __shared__ __align__(16) char smem[16384];
    char* smemA = smem;
    char* smemB = smem + 8192;
    const int w = threadIdx.x >> 6;
    const int lane = threadIdx.x & 63;
    const int row0 = blockIdx.x * 128;
    const int col0 = blockIdx.y * 128;
    const int quad = lane >> 4, l15 = lane & 15;
    const int wm = (w >> 1) * 64, wn = (w & 1) * 64;
    const int c0 = w * 2;
    const int srow = lane >> 2;
    const int skel = (lane & 3) * 8;
    // waves with wn==0 in blockIdx.y==0 also compute the 16-col el/er tile via MFMA
    const bool my_e = (blockIdx.y == 0) && ((w & 1) == 0);

    f32x4_t acc[4][4] = {};
    f32x4_t acce[4] = {};
    for (int k0 = 0; k0 < K; k0 += 32) {
        __syncthreads();
        {
            const __hip_bfloat16* gA0 = A + (size_t)(row0 + c0 * 16 + srow) * K + k0 + skel;
            const __hip_bfloat16* gB0 = Wt + (size_t)(col0 + c0 * 16 + srow) * K + k0 + skel;
            gld_lds16(gA0, smemA + c0 * 1024);
            gld_lds16(gA0 + (size_t)16 * K, smemA + (c0 + 1) * 1024);
            gld_lds16(gB0, smemB + c0 * 1024);
            gld_lds16(gB0 + (size_t)16 * K, smemB + (c0 + 1) * 1024);
        }
        __syncthreads();
        bf16x8_t a[4], b[4];
#pragma unroll
        for (int mi = 0; mi < 4; mi++)
            a[mi] = *reinterpret_cast<const bf16x8_t*>(smemA + (wm + mi * 16 + l15) * 64 + quad * 16);
#pragma unroll
        for (int ni = 0; ni < 4; ni++)
            b[ni] = *reinterpret_cast<const bf16x8_t*>(smemB + (wn + ni * 16 + l15) * 64 + quad * 16);
#pragma unroll
        for (int mi = 0; mi < 4; mi++)
#pragma unroll
            for (int ni = 0; ni < 4; ni++)
                acc[mi][ni] = __builtin_amdgcn_mfma_f32_16x16x32_bf16(a[mi], b[ni], acc[mi][ni], 0, 0, 0);
        if (my_e) {
            bf16x8_t b5 = *reinterpret_cast<const bf16x8_t*>(
                walr + (k0 >> 5) * 512 + l15 * 32 + quad * 8);
#pragma unroll
            for (int mi = 0; mi < 4; mi++)
                acce[mi] = __builtin_amdgcn_mfma_f32_16x16x32_bf16(a[mi], b5, acce[mi], 0, 0, 0);
        }
    }
    // epilogue: plain stores only (no cross-lane ops)
#pragma unroll
    for (int mi = 0; mi < 4; mi++) {
#pragma unroll
        for (int ni = 0; ni < 4; ni++) {
#pragma unroll
            for (int r = 0; r < 4; r++) {
                int row = row0 + wm + mi * 16 + quad * 4 + r;
                if (row < NN)
                    C[(size_t)row * 512 + col0 + wn + ni * 16 + l15] =
                        __float2bfloat16(acc[mi][ni][r]);
            }
        }
    }
    if (my_e) {
#pragma unroll
        for (int mi = 0; mi < 4; mi++) {
#pragma unroll
            for (int r = 0; r < 4; r++) {
                int row = row0 + wm + mi * 16 + quad * 4 + r;
                if (row < NN) {
                    float v = acce[mi][r];
                    if (l15 < 8) el[row * 8 + l15] = v;
                    else er[row * 8 + l15 - 8] = v;
                }
            }
        }
    }
}

// ---------- layer-3 MFMA GEMM + fused attn; C padded to 64 cols ----------
#define W3_LDSROW 520
__global__ __launch_bounds__(256) void gemm3_mfma(const __hip_bfloat16* __restrict__ A,
                                                  const __hip_bfloat16* __restrict__ W3t,
                                                  const float* __restrict__ al,
                                                  const float* __restrict__ ar,
                                                  __hip_bfloat16* __restrict__ C,
                                                  float* __restrict__ el,
                                                  float* __restrict__ er) {
    __shared__ __align__(16) __hip_bfloat16 wlds[48 * W3_LDSROW];
    for (int c = threadIdx.x; c < 48 * 64; c += 256) {
        int n = c >> 6, koff = (c & 63) * 8;
        *reinterpret_cast<uint4*>(&wlds[n * W3_LDSROW + koff]) =
            *reinterpret_cast<const uint4*>(W3t + n * 512 + koff);
    }
    __syncthreads();
    const int w = threadIdx.x >> 6;
    const int lane = threadIdx.x & 63;
    const int quad = lane >> 4, l15 = lane & 15;
    const int row0 = blockIdx.x * 64 + w * 16;

    float alv[3], arv[3];
#pragma unroll
    for (int c = 0; c < 3; c++) {
        int col = c * 16 + l15;
        alv[c] = (col < 40) ? al[col] : 0.f;
        arv[c] = (col < 40) ? ar[col] : 0.f;
    }

    f32x4_t acc[3] = {};
    const __hip_bfloat16* arow = A + (size_t)(row0 + l15) * 512;
#pragma unroll 4
    for (int k0 = 0; k0 < 512; k0 += 32) {
        bf16x8_t a = *reinterpret_cast<const bf16x8_t*>(arow + k0 + quad * 8);
#pragma unroll
        for (int c = 0; c < 3; c++) {
            bf16x8_t b = *reinterpret_cast<const bf16x8_t*>(
                &wlds[(c * 16 + l15) * W3_LDSROW + k0 + quad * 8]);
            acc[c] = __builtin_amdgcn_mfma_f32_16x16x32_bf16(a, b, acc[c], 0, 0, 0);
        }
    }
#pragma unroll
    for (int r = 0; r < 4; r++) {
        int row = row0 + quad * 4 + r;
        bool rok = row < NN;
        float pl = 0.f, pr = 0.f;
#pragma unroll
        for (int c = 0; c < 3; c++) {
            float v = acc[c][r];
            if (rok) C[(size_t)row * 64 + c * 16 + l15] = __float2bfloat16(v);
            pl += v * alv[c];
            pr += v * arv[c];
        }
        if (rok) C[(size_t)row * 64 + 48 + l15] = __float2bfloat16(0.f);
        pl += __shfl_xor(pl, 1, 64); pr += __shfl_xor(pr, 1, 64);
        pl += __shfl_xor(pl, 2, 64); pr += __shfl_xor(pr, 2, 64);
        pl += __shfl_xor(pl, 4, 64); pr += __shfl_xor(pr, 4, 64);
        pl += __shfl_xor(pl, 8, 64); pr += __shfl_xor(pr, 8, 64);
        if (l15 == 0 && rok) { el[row] = pl; er[row] = pr; }
    }
}

// ---------- agg layers 1-2: one wave/node, single-pass online softmax ----------
__global__ __launch_bounds__(256) void agg8_kernel(const __hip_bfloat16* __restrict__ feat,
                                                   const float* __restrict__ el,
                                                   const float* __restrict__ er,
                                                   const int* __restrict__ off,
                                                   const int* __restrict__ csr,
                                                   __hip_bfloat16* __restrict__ out) {
    int n = (blockIdx.x * blockDim.x + threadIdx.x) >> 6;
    int lane = threadIdx.x & 63;
    if (n >= NN) return;
    const int h8 = lane & 7;
    const int es = lane >> 3;
    const int hd = lane >> 3;
    int rs = off[n], re = off[n + 1];
    float er_n = er[n * 8 + h8];

    float m = -INFINITY, lsum = 0.f;
    float acc[8] = {};
    for (int base = rs; base < re; base += 8) {
        int e = base + es;
        bool valid = e < re;
        int s = valid ? csr[e] : 0;
        float t = el[s * 8 + h8] + er_n;
        float x = (t >= 0.f) ? t : 0.2f * t;
        if (!valid) x = -INFINITY;
        float gm = x;
        gm = fmaxf(gm, __shfl_xor(gm, 8, 64));
        gm = fmaxf(gm, __shfl_xor(gm, 16, 64));
        gm = fmaxf(gm, __shfl_xor(gm, 32, 64));
        float nm = fmaxf(m, gm);
        float scale = __expf(m - nm);
        float p = __expf(x - nm);
        lsum = lsum * scale + p;
        float sc = __shfl(scale, hd, 64);
#pragma unroll
        for (int d = 0; d < 8; ++d) acc[d] *= sc;
#pragma unroll
        for (int j = 0; j < 8; ++j) {
            int sj = __shfl(s, j * 8, 64);
            float pj = __shfl(p, j * 8 + hd, 64);
            uint4 q = *reinterpret_cast<const uint4*>(feat + (size_t)sj * 512 + lane * 8);
            float f[8];
            unpack8(q, f);
#pragma unroll
            for (int d = 0; d < 8; ++d) acc[d] += pj * f[d];
        }
        m = nm;
    }
    lsum += __shfl_xor(lsum, 8, 64);
    lsum += __shfl_xor(lsum, 16, 64);
    lsum += __shfl_xor(lsum, 32, 64);
    float lh = __shfl(lsum, hd, 64);
    float inv = (lh > 0.f) ? 1.f / lh : 0.f;
    bf16x8_t o8;
#pragma unroll
    for (int d = 0; d < 8; ++d) o8[d] = (__bf16)(acc[d] * inv);
    *reinterpret_cast<bf16x8_t*>(out + (size_t)n * 512 + lane * 8) = o8;
}

// ---------- agg layer 3: H=1, feat padded to 64 cols; 8 edges per load ----------
__global__ __launch_bounds__(256) void agg3_kernel(const __hip_bfloat16* __restrict__ feat,
                                                   const float* __restrict__ el,
                                                   const float* __restrict__ er,
                                                   const int* __restrict__ off,
                                                   const int* __restrict__ csr,
                                                   float* __restrict__ out) {
    int n = (blockIdx.x * blockDim.x + threadIdx.x) >> 6;
    int lane = threadIdx.x & 63;
    if (n >= NN) return;
    const int es = lane >> 3;
    const int dc = lane & 7;
    int rs = off[n], re = off[n + 1];
    float er_n = er[n];

    float m = -INFINITY, lsum = 0.f;
    float acc[8] = {};
    for (int base = rs; base < re; base += 8) {
        int e = base + es;
        bool valid = e < re;
        int s = valid ? csr[e] : 0;
        float t = el[s] + er_n;
        float x = (t >= 0.f) ? t : 0.2f * t;
        if (!valid) x = -INFINITY;
        float gm = x;
        gm = fmaxf(gm, __shfl_xor(gm, 8, 64));
        gm = fmaxf(gm, __shfl_xor(gm, 16, 64));
        gm = fmaxf(gm, __shfl_xor(gm, 32, 64));
        float nm = fmaxf(m, gm);
        float scale = __expf(m - nm);
        float p = __expf(x - nm);
        lsum = lsum * scale + p;
        uint4 q = *reinterpret_cast<const uint4*>(feat + (size_t)s * 64 + dc * 8);
        float f[8];
        unpack8(q, f);
#pragma unroll
        for (int d = 0; d < 8; ++d) acc[d] = acc[d] * scale + p * f[d];
        m = nm;
    }
    lsum += __shfl_xor(lsum, 8, 64);
    lsum += __shfl_xor(lsum, 16, 64);
    lsum += __shfl_xor(lsum, 32, 64);
#pragma unroll
    for (int d = 0; d < 8; ++d) {
        acc[d] += __shfl_xor(acc[d], 8, 64);
        acc[d] += __shfl_xor(acc[d], 16, 64);
        acc[d] += __shfl_xor(acc[d], 32, 64);
    }
    float inv = (lsum > 0.f) ? 1.f / lsum : 0.f;
    if (es == 0 && dc < 5) {
        float4 o0 = make_float4(acc[0] * inv, acc[1] * inv, acc[2] * inv, acc[3] * inv);
        float4 o1 = make_float4(acc[4] * inv, acc[5] * inv, acc[6] * inv, acc[7] * inv);
        *reinterpret_cast<float4*>(out + (size_t)n * 40 + dc * 8) = o0;
        *reinterpret_cast<float4*>(out + (size_t)n * 40 + dc * 8 + 4) = o1;
    }
}

extern "C" void kernel_launch(void* const* d_in, const int* in_sizes, int n_in,
                              void* d_out, int out_size, void* d_ws, size_t ws_size,
                              hipStream_t stream) {
    const float* features = (const float*)d_in[0];
    const int* src = (const int*)d_in[1];
    const int* dst = (const int*)d_in[2];
    const float* W1 = (const float*)d_in[3];
    const float* al1 = (const float*)d_in[4];
    const float* ar1 = (const float*)d_in[5];
    const float* W2 = (const float*)d_in[6];
    const float* al2 = (const float*)d_in[7];
    const float* ar2 = (const float*)d_in[8];
    const float* W3 = (const float*)d_in[9];
    const float* al3 = (const float*)d_in[10];
    const float* ar3 = (const float*)d_in[11];

    char* ws = (char*)d_ws;
    size_t o = 0;
    auto carve = [&](size_t bytes) -> void* {
        o = (o + 255) & ~(size_t)255;
        void* p = ws + o;
        o += bytes;
        return p;
    };
    __hip_bfloat16* Abf1 = (__hip_bfloat16*)carve((size_t)MPAD * 256 * 2);
    __hip_bfloat16* Fbf = (__hip_bfloat16*)carve((size_t)MPAD * 512 * 2);
    __hip_bfloat16* Gbf = (__hip_bfloat16*)carve((size_t)MPAD * 512 * 2);
    __hip_bfloat16* W1t = (__hip_bfloat16*)carve((size_t)512 * 256 * 2);
    __hip_bfloat16* W2t = (__hip_bfloat16*)carve((size_t)512 * 512 * 2);
    __hip_bfloat16* W3t = (__hip_bfloat16*)carve((size_t)48 * 512 * 2);
    __hip_bfloat16* walr1 = (__hip_bfloat16*)carve((size_t)16 * 256 * 2);
    __hip_bfloat16* walr2 = (__hip_bfloat16*)carve((size_t)16 * 512 * 2);
    float* el = (float*)carve((size_t)NN * 8 * 4);
    float* er = (float*)carve((size_t)NN * 8 * 4);
    float* el3 = (float*)carve((size_t)NN * 4);
    float* er3 = (float*)carve((size_t)NN * 4);
    int* deg = (int*)carve((size_t)NN * 4);
    int* offp = (int*)carve((size_t)(NN + 1) * 4);
    int* cur = (int*)carve((size_t)NN * 4);
    int* csr = (int*)carve((size_t)NE * 4);

    hipMemsetAsync(deg, 0, (size_t)NN * 4, stream);
    prep_kernel<<<4096, 256, 0, stream>>>(features, Abf1, dst, deg, W1, W1t, W2, W2t, W3, W3t,
                                          al1, ar1, al2, ar2, walr1, walr2);
    scan_kernel<<<1, 1024, 0, stream>>>(deg, offp, cur, NN);
    scatter_kernel<<<(NE + 255) / 256, 256, 0, stream>>>(src, dst, cur, csr);

    const int gmm = MPAD / 128;       // 391
    const int aggblk = (NN + 3) / 4;  // 12500
    // ---- layer 1 ----
    gemm_bt_fused<<<dim3(gmm, 4), 256, 0, stream>>>(Abf1, W1t, walr1, Fbf, el, er, 256);
    agg8_kernel<<<aggblk, 256, 0, stream>>>(Fbf, el, er, offp, csr, Gbf);
    // ---- layer 2 ----
    gemm_bt_fused<<<dim3(gmm, 4), 256, 0, stream>>>(Gbf, W2t, walr2, Fbf, el, er, 512);
    agg8_kernel<<<aggblk, 256, 0, stream>>>(Fbf, el, er, offp, csr, Gbf);
    // ---- layer 3 (feat padded to 64 cols in Fbf) ----
    gemm3_mfma<<<MPAD / 64, 256, 0, stream>>>(Gbf, W3t, al3, ar3, Fbf, el3, er3);
    agg3_kernel<<<aggblk, 256, 0, stream>>>(Fbf, el3, er3, offp, csr, (float*)d_out);
}